// Round 6
// baseline (1033.705 us; speedup 1.0000x reference)
//
#include <hip/hip_runtime.h>
#include <hip/hip_bf16.h>

// Problem constants (fixed by reference)
#define T_STEPS 256
#define BATCH   16
#define HID     512
#define VOCAB   32000
#define M_TOT   (T_STEPS * BATCH)   // 4096
#define KT_DEC  16                  // 512/32

typedef __attribute__((ext_vector_type(8))) short s8v;   // 8 bf16 (4 VGPRs)
typedef __attribute__((ext_vector_type(4))) float f4v;   // 4 f32 accum
typedef unsigned short ushort_t;

__device__ __forceinline__ unsigned short f2bf_rne(float f) {
  unsigned u = __float_as_uint(f);
  unsigned r = u + 0x7fffu + ((u >> 16) & 1u);
  return (unsigned short)(r >> 16);
}
__device__ __forceinline__ float bf2f(unsigned short s) {
  return __uint_as_float(((unsigned)s) << 16);
}
// Tile unit layout: tile = [128 rows r][4 k-groups kg] of s8v (16B) units.
__device__ __forceinline__ int unit_swz(int r, int kg) {
  return r * 4 + (kg ^ ((r >> 1) & 3));
}
// async global->LDS, 16B/lane; LDS dest = wave-uniform base + lane*16 (HW)
__device__ __forceinline__ void gload16(const void* g, void* l) {
  __builtin_amdgcn_global_load_lds(
      (const __attribute__((address_space(1))) unsigned int*)g,
      (__attribute__((address_space(3))) unsigned int*)l, 16, 0, 0);
}
#define MFMA16(a, b, c) __builtin_amdgcn_mfma_f32_16x16x32_bf16((a), (b), (c), 0, 0, 0)

// ---------------------------------------------------------------------------
// K1 "head": blocks 0..127  = pre-GEMM; blocks 128..4127 = dec_w presplit.
// (unchanged)
// ---------------------------------------------------------------------------
__global__ __launch_bounds__(256, 2) void head_kernel(
    const int* __restrict__ tok, const float* __restrict__ emb,
    const float* __restrict__ w1, const float* __restrict__ b1f,
    float* __restrict__ pre,
    const float* __restrict__ dec_w, ushort_t* __restrict__ bhi,
    ushort_t* __restrict__ blo, int do_split) {
  if (blockIdx.x >= 128) {
    if (!do_split) return;
    const int pid = blockIdx.x - 128;
    const int nt = pid >> 4, ks = pid & 15;
    const int tid = threadIdx.x;
#pragma unroll
    for (int h = 0; h < 2; ++h) {
      int us = h * 256 + tid;
      int r = us >> 2, kg = us & 3;
      const float* src = dec_w + (size_t)(nt * 128 + r) * HID + ks * 32 + kg * 8;
      float4 v0 = *(const float4*)src;
      float4 v1 = *(const float4*)(src + 4);
      float av[8] = {v0.x, v0.y, v0.z, v0.w, v1.x, v1.y, v1.z, v1.w};
      s8v hi, lo;
#pragma unroll
      for (int j = 0; j < 8; ++j) {
        unsigned short hh = f2bf_rne(av[j]);
        hi[j] = (short)hh;
        lo[j] = (short)f2bf_rne(av[j] - bf2f(hh));
      }
      size_t base = ((size_t)(nt * 16 + ks) * 512 + unit_swz(r, kg)) * 8;
      *(s8v*)(bhi + base) = hi;
      *(s8v*)(blo + base) = lo;
    }
    return;
  }
  __shared__ s8v Ah[512], Al[512], Bh[512], Bl[512];
  const int mt = blockIdx.x & 31, nt = blockIdx.x >> 5;
  const int tid = threadIdx.x;
  const int lane = tid & 63, wave = tid >> 6;
  const int wm = wave >> 1, wn = wave & 1;
  const int m0 = mt * 128, n0 = nt * 128;
  f4v acc[4][4] = {};

  for (int ks = 0; ks < 16; ++ks) {
    const int k0 = ks * 32;
#pragma unroll
    for (int c = 0; c < 2; ++c) {
      int idx = c * 256 + tid;
      int r = idx >> 2, kg = idx & 3;
      int kgp = kg ^ (r & 3);
      int t_ = tok[m0 + r];
      const float* as = emb + (size_t)t_ * HID + k0 + kg * 8;
      float4 a0 = *(const float4*)as;
      float4 a1 = *(const float4*)(as + 4);
      float av[8] = {a0.x, a0.y, a0.z, a0.w, a1.x, a1.y, a1.z, a1.w};
      s8v ah, al;
#pragma unroll
      for (int j = 0; j < 8; ++j) {
        unsigned short h = f2bf_rne(av[j]);
        ah[j] = (short)h;
        al[j] = (short)f2bf_rne(av[j] - bf2f(h));
      }
      Ah[r * 4 + kgp] = ah;  Al[r * 4 + kgp] = al;
      const float* bs = w1 + (size_t)(n0 + r) * 1024 + k0 + kg * 8;
      float4 b0 = *(const float4*)bs;
      float4 b1v = *(const float4*)(bs + 4);
      float bv[8] = {b0.x, b0.y, b0.z, b0.w, b1v.x, b1v.y, b1v.z, b1v.w};
      s8v bh, bl;
#pragma unroll
      for (int j = 0; j < 8; ++j) {
        unsigned short h = f2bf_rne(bv[j]);
        bh[j] = (short)h;
        bl[j] = (short)f2bf_rne(bv[j] - bf2f(h));
      }
      Bh[r * 4 + kgp] = bh;  Bl[r * 4 + kgp] = bl;
    }
    __syncthreads();
    s8v afh[4], afl[4], bfh[4], bfl[4];
#pragma unroll
    for (int f = 0; f < 4; ++f) {
      int rA = wm * 64 + f * 16 + (lane & 15);
      afh[f] = Ah[rA * 4 + ((lane >> 4) ^ (rA & 3))];
      afl[f] = Al[rA * 4 + ((lane >> 4) ^ (rA & 3))];
      int rB = wn * 64 + f * 16 + (lane & 15);
      bfh[f] = Bh[rB * 4 + ((lane >> 4) ^ (rB & 3))];
      bfl[f] = Bl[rB * 4 + ((lane >> 4) ^ (rB & 3))];
    }
    // independent-first ordering (same per-acc order: hh, lh, hl)
#pragma unroll
    for (int i = 0; i < 4; ++i)
#pragma unroll
      for (int j = 0; j < 4; ++j)
        acc[i][j] = MFMA16(afh[i], bfh[j], acc[i][j]);
#pragma unroll
    for (int i = 0; i < 4; ++i)
#pragma unroll
      for (int j = 0; j < 4; ++j)
        acc[i][j] = MFMA16(afl[i], bfh[j], acc[i][j]);
#pragma unroll
    for (int i = 0; i < 4; ++i)
#pragma unroll
      for (int j = 0; j < 4; ++j)
        acc[i][j] = MFMA16(afh[i], bfl[j], acc[i][j]);
    __syncthreads();
  }
#pragma unroll
  for (int j = 0; j < 4; ++j) {
    int col = n0 + wn * 64 + j * 16 + (lane & 15);
    float bias = b1f[col];
#pragma unroll
    for (int i = 0; i < 4; ++i)
#pragma unroll
      for (int rg = 0; rg < 4; ++rg) {
        int row = m0 + wm * 64 + i * 16 + (lane >> 4) * 4 + rg;
        pre[(size_t)row * HID + col] = acc[i][j][rg] + bias;
      }
  }
}

// ---------------------------------------------------------------------------
// K2: barrier-free persistent scan. Round-6 change: all-512-thread finish
// (2 LDS reads + 3 shfl_xor hops, 8 lanes/output) -> h store lands earlier.
// ---------------------------------------------------------------------------
__global__ __launch_bounds__(512) void scan_kernel(
    const float* __restrict__ w1, const float* __restrict__ pre,
    unsigned long long* hbuf,
    ushort_t* __restrict__ o_hi, ushort_t* __restrict__ o_lo,
    float* __restrict__ h_last_out) {
  __shared__ float wLds[16384];
  __shared__ float hs[2][512];
  __shared__ float part[2][528];

  const int bp = blockIdx.x & 7;
  const int sg = blockIdx.x >> 3;
  const int b0 = bp * 2;
  const int tid = threadIdx.x;

#pragma unroll
  for (int k = 0; k < 8; ++k) {
    int uid = k * 512 + tid;
    int r = uid >> 7, u = uid & 127;
    float4 v = *(const float4*)(w1 + (size_t)(sg * 32 + r) * 1024 + 512 + u * 4);
    int dst = r * 512 + (u >> 3) * 32 + (((u & 7) ^ (r & 7)) << 2);
    *(float4*)(&wLds[dst]) = v;
  }
  __syncthreads();

  const int i = tid & 31, s = tid >> 5;
  const int rowbase = i * 512 + s * 32;
  const int isw = i & 7;
  // finish-phase roles: output g = tid>>3 (0..63: bl=g>>5, ii=g&31), k = tid&7
  const int g = tid >> 3, k8 = tid & 7;
  const int gbl = g >> 5, gii = g & 31;

  for (int t = 0; t < T_STEPS; ++t) {
    const int cur = t & 1, nxt = cur ^ 1;

    // prefetch pre for this output's finisher lane (hides under poll)
    float pv = 0.f;
    if (k8 == 0)
      pv = pre[(size_t)(t * BATCH + b0 + gbl) * HID + sg * 32 + gii];

    unsigned long long* p0 = hbuf + ((size_t)cur * BATCH + b0) * HID + tid;
    unsigned long long* p1 = hbuf + ((size_t)cur * BATCH + b0 + 1) * HID + tid;
    unsigned long long e0 = __hip_atomic_load(p0, __ATOMIC_RELAXED, __HIP_MEMORY_SCOPE_AGENT);
    unsigned long long e1 = __hip_atomic_load(p1, __ATOMIC_RELAXED, __HIP_MEMORY_SCOPE_AGENT);
    int spins = 0;
    while ((unsigned)(e0 >> 32) != (unsigned)t || (unsigned)(e1 >> 32) != (unsigned)t) {
      __builtin_amdgcn_s_sleep(1);
      if ((unsigned)(e0 >> 32) != (unsigned)t)
        e0 = __hip_atomic_load(p0, __ATOMIC_RELAXED, __HIP_MEMORY_SCOPE_AGENT);
      if ((unsigned)(e1 >> 32) != (unsigned)t)
        e1 = __hip_atomic_load(p1, __ATOMIC_RELAXED, __HIP_MEMORY_SCOPE_AGENT);
      if (++spins > (1 << 20)) break;
    }
    hs[0][tid] = __uint_as_float((unsigned)e0);
    hs[1][tid] = __uint_as_float((unsigned)e1);
    __syncthreads();   // sync #1: hs ready; also orders part reuse

    float a0 = 0.f, a1 = 0.f;
#pragma unroll
    for (int u = 0; u < 8; ++u) {
      float4 w = *(const float4*)(&wLds[rowbase + ((u ^ isw) << 2)]);
      float4 h0 = *(const float4*)(&hs[0][s * 32 + (u << 2)]);
      float4 h1 = *(const float4*)(&hs[1][s * 32 + (u << 2)]);
      a0 += w.x * h0.x + w.y * h0.y + w.z * h0.z + w.w * h0.w;
      a1 += w.x * h1.x + w.y * h1.y + w.z * h1.z + w.w * h1.w;
    }
    part[0][s * 33 + i] = a0;
    part[1][s * 33 + i] = a1;
    __syncthreads();   // sync #2: part ready

    // --- finish: all 512 threads; 8 lanes per output, shuffle tree ---
    float v = part[gbl][(2 * k8) * 33 + gii] + part[gbl][(2 * k8 + 1) * 33 + gii];
    v += __shfl_xor(v, 1);
    v += __shfl_xor(v, 2);
    v += __shfl_xor(v, 4);
    if (k8 == 0) {
      float hn = tanhf(v + pv);
      int b = b0 + gbl;
      unsigned long long ev = ((unsigned long long)(unsigned)(t + 1) << 32) |
                              (unsigned long long)__float_as_uint(hn);
      __hip_atomic_store(hbuf + ((size_t)nxt * BATCH + b) * HID + sg * 32 + gii, ev,
                         __ATOMIC_RELAXED, __HIP_MEMORY_SCOPE_AGENT);
      int m = t * BATCH + b;
      int mt = m >> 7, r = m & 127;
      int kg = gii >> 3, e = gii & 7;
      size_t ao = ((size_t)(mt * 16 + sg) * 512 + unit_swz(r, kg)) * 8 + e;
      unsigned short hi_ = f2bf_rne(hn);
      o_hi[ao] = hi_;
      o_lo[ao] = f2bf_rne(hn - bf2f(hi_));
      if (t == T_STEPS - 1) h_last_out[(size_t)b * HID + sg * 32 + gii] = hn;
    }
  }
}

// ---------------------------------------------------------------------------
// K3 v3b: 256x256 deep-pipelined decode GEMM. Round-6 change: MFMA pass
// reorder — 3 passes of 8 INDEPENDENT MFMAs per phase (same per-acc order:
// hh, lh, hl -> bit-identical). Everything else (barriers, counted vmcnt,
// staging, swizzle) identical to round 5.
// ---------------------------------------------------------------------------
__global__ __launch_bounds__(512, 2) void dec_gemm_v3(
    const ushort_t* __restrict__ ahi, const ushort_t* __restrict__ alo,
    const ushort_t* __restrict__ bhi, const ushort_t* __restrict__ blo,
    const float* __restrict__ dec_b, float* __restrict__ out) {
  extern __shared__ s8v SB[];   // 2 x 4096 units of 16B
  const int bid = blockIdx.x;
  const int wg  = (bid & 7) * 250 + (bid >> 3);   // XCD-bijective (2000 = 8*250)
  const int mt2 = wg & 15, nt2 = wg >> 4;         // mt fastest: B-panel L2 reuse
  const int tid = threadIdx.x, lane = tid & 63, wv = tid >> 6;
  const int wm = wv >> 2, wn = wv & 3;            // 2 x 4 wave grid
  const int kgl = lane >> 4, lr = lane & 15;

  const ushort_t* gsrc;
  int gtile;
  if (wv < 4) { gsrc = (wv < 2) ? ahi : alo; gtile = mt2 * 2 + (wv & 1); }
  else        { gsrc = (wv < 6) ? bhi : blo; gtile = nt2 * 2 + (wv & 1); }

  f4v acc[8][4] = {};

  {
    const char* g0 = (const char*)(gsrc + (size_t)(gtile * 16 + 0) * 4096);
    const char* g1 = (const char*)(gsrc + (size_t)(gtile * 16 + 1) * 4096);
    char* l0 = (char*)SB + wv * 8192;
    char* l1 = (char*)SB + 65536 + wv * 8192;
#pragma unroll
    for (int p = 0; p < 8; ++p) gload16(g0 + p * 1024 + (size_t)lane * 16, l0 + p * 1024);
#pragma unroll
    for (int p = 0; p < 8; ++p) gload16(g1 + p * 1024 + (size_t)lane * 16, l1 + p * 1024);
    asm volatile("s_waitcnt vmcnt(8)" ::: "memory");   // kt0 landed
    __builtin_amdgcn_sched_barrier(0);
    __builtin_amdgcn_s_barrier();
    __builtin_amdgcn_sched_barrier(0);
  }

  for (int kt = 0; kt < KT_DEC; ++kt) {
    const int c = kt & 1;
    const s8v* B0 = SB + c * 4096;

    s8v bfh[4], bfl[4];
    const int tB = wn >> 1;
#pragma unroll
    for (int g = 0; g < 4; ++g) {
      int rB = (wn & 1) * 64 + g * 16 + lr;
      int u = unit_swz(rB, kgl);
      bfh[g] = B0[(4 + tB) * 512 + u];
      bfl[g] = B0[(6 + tB) * 512 + u];
    }
#pragma unroll
    for (int fp = 0; fp < 4; ++fp) {      // phase fp: rows f=2fp, 2fp+1
      const int f0 = fp * 2, f1 = fp * 2 + 1;
      int uA0 = unit_swz(f0 * 16 + lr, kgl);
      int uA1 = unit_swz(f1 * 16 + lr, kgl);
      s8v ah0 = B0[wm * 512 + uA0];
      s8v al0 = B0[(2 + wm) * 512 + uA0];
      s8v ah1 = B0[wm * 512 + uA1];
      s8v al1 = B0[(2 + wm) * 512 + uA1];
      __builtin_amdgcn_s_setprio(1);
      // pass 1: hi*hi  (8 independent)
#pragma unroll
      for (int j = 0; j < 4; ++j) {
        acc[f0][j] = MFMA16(ah0, bfh[j], acc[f0][j]);
        acc[f1][j] = MFMA16(ah1, bfh[j], acc[f1][j]);
      }
      // pass 2: lo*hi  (8 independent; same-acc distance 8)
#pragma unroll
      for (int j = 0; j < 4; ++j) {
        acc[f0][j] = MFMA16(al0, bfh[j], acc[f0][j]);
        acc[f1][j] = MFMA16(al1, bfh[j], acc[f1][j]);
      }
      // pass 3: hi*lo
#pragma unroll
      for (int j = 0; j < 4; ++j) {
        acc[f0][j] = MFMA16(ah0, bfl[j], acc[f0][j]);
        acc[f1][j] = MFMA16(ah1, bfl[j], acc[f1][j]);
      }
      __builtin_amdgcn_s_setprio(0);
    }
    asm volatile("s_waitcnt lgkmcnt(0)" ::: "memory");
    __builtin_amdgcn_sched_barrier(0);
    __builtin_amdgcn_s_barrier();           // safe to overwrite buf c
    __builtin_amdgcn_sched_barrier(0);
    if (kt + 2 < KT_DEC) {
      const char* g = (const char*)(gsrc + (size_t)(gtile * 16 + kt + 2) * 4096);
      char* l = (char*)SB + c * 65536 + wv * 8192;
#pragma unroll
      for (int p = 0; p < 8; ++p) gload16(g + p * 1024 + (size_t)lane * 16, l + p * 1024);
      asm volatile("s_waitcnt vmcnt(8)" ::: "memory");   // kt+1 landed
    } else {
      asm volatile("s_waitcnt vmcnt(0)" ::: "memory");   // tail drain
    }
    __builtin_amdgcn_sched_barrier(0);
    __builtin_amdgcn_s_barrier();           // kt+1 visible to all waves
    __builtin_amdgcn_sched_barrier(0);
  }

  const int m0 = mt2 * 256, n0 = nt2 * 256;
#pragma unroll
  for (int j = 0; j < 4; ++j) {
    int col = n0 + wn * 64 + j * 16 + lr;
    float bias = dec_b[col];
#pragma unroll
    for (int f = 0; f < 8; ++f) {
      int rowb = m0 + wm * 128 + f * 16 + kgl * 4;
#pragma unroll
      for (int rg = 0; rg < 4; ++rg)
        out[(size_t)(rowb + rg) * VOCAB + col] = acc[f][j][rg] + bias;
    }
  }
}

// ---------------------------------------------------------------------------
// K3 fallback (ws too small for presplit): unchanged.
// ---------------------------------------------------------------------------
__global__ __launch_bounds__(256, 2) void dec_gemm_fb(
    const ushort_t* __restrict__ o_hi, const ushort_t* __restrict__ o_lo,
    const float* __restrict__ dec_w, const float* __restrict__ dec_b,
    float* __restrict__ out) {
  __shared__ s8v Ah[512], Al[512], Bh[512], Bl[512];
  const int mt = blockIdx.x, nt = blockIdx.y;
  const int tid = threadIdx.x;
  const int lane = tid & 63, wave = tid >> 6;
  const int wm = wave >> 1, wn = wave & 1;
  const int kgl = lane >> 4, lr = lane & 15;
  const int m0 = mt * 128, n0 = nt * 128;
  f4v acc[4][4] = {};

  for (int ks = 0; ks < KT_DEC; ++ks) {
    const int k0 = ks * 32;
#pragma unroll
    for (int c = 0; c < 2; ++c) {
      int idx = c * 256 + tid;
      size_t abase = (size_t)(mt * 16 + ks) * 4096 + (size_t)idx * 8;
      Ah[idx] = *(const s8v*)(o_hi + abase);
      Al[idx] = *(const s8v*)(o_lo + abase);
      int r = idx >> 2, kg = idx & 3;
      const float* bs = dec_w + (size_t)(n0 + r) * HID + k0 + kg * 8;
      float4 b0 = *(const float4*)bs;
      float4 b1v = *(const float4*)(bs + 4);
      float bv[8] = {b0.x, b0.y, b0.z, b0.w, b1v.x, b1v.y, b1v.z, b1v.w};
      s8v bh, bl;
#pragma unroll
      for (int j = 0; j < 8; ++j) {
        unsigned short h = f2bf_rne(bv[j]);
        bh[j] = (short)h;
        bl[j] = (short)f2bf_rne(bv[j] - bf2f(h));
      }
      int ub = unit_swz(r, kg);
      Bh[ub] = bh;  Bl[ub] = bl;
    }
    __syncthreads();
    s8v afh[4], afl[4], bfh[4], bfl[4];
#pragma unroll
    for (int f = 0; f < 4; ++f) {
      int rA = wm * 64 + f * 16 + lr;
      int uA = unit_swz(rA, kgl);
      afh[f] = Ah[uA];  afl[f] = Al[uA];
      int rB = wn * 64 + f * 16 + lr;
      int uB = unit_swz(rB, kgl);
      bfh[f] = Bh[uB];  bfl[f] = Bl[uB];
    }
#pragma unroll
    for (int i = 0; i < 4; ++i)
#pragma unroll
      for (int j = 0; j < 4; ++j)
        acc[i][j] = MFMA16(afh[i], bfh[j], acc[i][j]);
#pragma unroll
    for (int i = 0; i < 4; ++i)
#pragma unroll
      for (int j = 0; j < 4; ++j)
        acc[i][j] = MFMA16(afl[i], bfh[j], acc[i][j]);
#pragma unroll
    for (int i = 0; i < 4; ++i)
#pragma unroll
      for (int j = 0; j < 4; ++j)
        acc[i][j] = MFMA16(afh[i], bfl[j], acc[i][j]);
    __syncthreads();
  }
#pragma unroll
  for (int j = 0; j < 4; ++j) {
    int col = n0 + wn * 64 + j * 16 + lr;
    float bias = dec_b[col];
#pragma unroll
    for (int i = 0; i < 4; ++i)
#pragma unroll
      for (int rg = 0; rg < 4; ++rg) {
        int row = m0 + wm * 64 + i * 16 + (lane >> 4) * 4 + rg;
        out[(size_t)row * VOCAB + col] = acc[i][j][rg] + bias;
      }
  }
}

// ---------------------------------------------------------------------------
// Workspace layout (bytes):
//   [0,       128 KiB)   hbuf: u64[2][16][512] (tag|f32)  (zeroed each call)
//   [1 MiB,    9 MiB)    pre : 4096 x 512 f32
//   [16 MiB,  20 MiB)    o_hi: tile-ready A hi (32x16 tiles x 8 KiB)
//   [20 MiB,  24 MiB)    o_lo: tile-ready A lo
//   [24 MiB,  ~55 MiB)   bhi : tile-ready dec_w hi (250x16 tiles x 8 KiB)
//   [56 MiB,  ~87 MiB)   blo : tile-ready dec_w lo
// ---------------------------------------------------------------------------
extern "C" void kernel_launch(void* const* d_in, const int* in_sizes, int n_in,
                              void* d_out, int out_size, void* d_ws, size_t ws_size,
                              hipStream_t stream) {
  (void)in_sizes; (void)n_in; (void)out_size;
  const int*   tok   = (const int*)d_in[0];
  const float* emb   = (const float*)d_in[2];
  const float* w1    = (const float*)d_in[3];
  const float* b1    = (const float*)d_in[4];
  const float* dec_w = (const float*)d_in[5];
  const float* dec_b = (const float*)d_in[6];
  char* ws = (char*)d_ws;
  unsigned long long* hbuf = (unsigned long long*)(ws);
  float* pre  = (float*)(ws + (1u << 20));
  ushort_t* o_hi = (ushort_t*)(ws + 16u * (1u << 20));
  ushort_t* o_lo = (ushort_t*)(ws + 20u * (1u << 20));
  ushort_t* bhi  = (ushort_t*)(ws + 24u * (1u << 20));
  ushort_t* blo  = (ushort_t*)(ws + 56u * (1u << 20));
  float* out = (float*)d_out;

  const int big = (ws_size >= (size_t)92 * 1024 * 1024) ? 1 : 0;

  hipMemsetAsync(ws, 0, 131072, stream);   // tag=0, h0=0
  head_kernel<<<dim3(4128), dim3(256), 0, stream>>>(
      tok, emb, w1, b1, pre, dec_w, bhi, blo, big);
  scan_kernel<<<dim3(128), dim3(512), 0, stream>>>(
      w1, pre, hbuf, o_hi, o_lo, out + (size_t)M_TOT * VOCAB);
  if (big) {
    hipFuncSetAttribute((const void*)dec_gemm_v3,
                        hipFuncAttributeMaxDynamicSharedMemorySize, 131072);
    dec_gemm_v3<<<dim3(2000), dim3(512), 131072, stream>>>(
        o_hi, o_lo, bhi, blo, dec_b, out);
  } else {
    dec_gemm_fb<<<dim3(32, 250), dim3(256), 0, stream>>>(o_hi, o_lo, dec_w, dec_b, out);
  }
}

// Round 7
// 927.874 us; speedup vs baseline: 1.1141x; 1.1141x over previous
//
#include <hip/hip_runtime.h>
#include <hip/hip_bf16.h>

// Problem constants (fixed by reference)
#define T_STEPS 256
#define BATCH   16
#define HID     512
#define VOCAB   32000
#define M_TOT   (T_STEPS * BATCH)   // 4096
#define KT_DEC  16                  // 512/32

typedef __attribute__((ext_vector_type(8))) short s8v;    // 8 bf16 (4 VGPRs)
typedef __attribute__((ext_vector_type(4))) float f4v;    // 4 f32 accum
typedef __attribute__((ext_vector_type(16))) float f16v;  // 16 f32 accum (32x32)
typedef unsigned short ushort_t;

__device__ __forceinline__ unsigned short f2bf_rne(float f) {
  unsigned u = __float_as_uint(f);
  unsigned r = u + 0x7fffu + ((u >> 16) & 1u);
  return (unsigned short)(r >> 16);
}
__device__ __forceinline__ float bf2f(unsigned short s) {
  return __uint_as_float(((unsigned)s) << 16);
}
// Tile unit layout: tile = [128 rows r][4 k-groups kg] of s8v (16B) units.
__device__ __forceinline__ int unit_swz(int r, int kg) {
  return r * 4 + (kg ^ ((r >> 1) & 3));
}
// async global->LDS, 16B/lane; LDS dest = wave-uniform base + lane*16 (HW)
__device__ __forceinline__ void gload16(const void* g, void* l) {
  __builtin_amdgcn_global_load_lds(
      (const __attribute__((address_space(1))) unsigned int*)g,
      (__attribute__((address_space(3))) unsigned int*)l, 16, 0, 0);
}
#define MFMA16(a, b, c) __builtin_amdgcn_mfma_f32_16x16x32_bf16((a), (b), (c), 0, 0, 0)
#define MFMA32(a, b, c) __builtin_amdgcn_mfma_f32_32x32x16_bf16((a), (b), (c), 0, 0, 0)

// ---------------------------------------------------------------------------
// K1 "head": blocks 0..127  = pre-GEMM; blocks 128..4127 = dec_w presplit.
// (unchanged)
// ---------------------------------------------------------------------------
__global__ __launch_bounds__(256, 2) void head_kernel(
    const int* __restrict__ tok, const float* __restrict__ emb,
    const float* __restrict__ w1, const float* __restrict__ b1f,
    float* __restrict__ pre,
    const float* __restrict__ dec_w, ushort_t* __restrict__ bhi,
    ushort_t* __restrict__ blo, int do_split) {
  if (blockIdx.x >= 128) {
    if (!do_split) return;
    const int pid = blockIdx.x - 128;
    const int nt = pid >> 4, ks = pid & 15;
    const int tid = threadIdx.x;
#pragma unroll
    for (int h = 0; h < 2; ++h) {
      int us = h * 256 + tid;
      int r = us >> 2, kg = us & 3;
      const float* src = dec_w + (size_t)(nt * 128 + r) * HID + ks * 32 + kg * 8;
      float4 v0 = *(const float4*)src;
      float4 v1 = *(const float4*)(src + 4);
      float av[8] = {v0.x, v0.y, v0.z, v0.w, v1.x, v1.y, v1.z, v1.w};
      s8v hi, lo;
#pragma unroll
      for (int j = 0; j < 8; ++j) {
        unsigned short hh = f2bf_rne(av[j]);
        hi[j] = (short)hh;
        lo[j] = (short)f2bf_rne(av[j] - bf2f(hh));
      }
      size_t base = ((size_t)(nt * 16 + ks) * 512 + unit_swz(r, kg)) * 8;
      *(s8v*)(bhi + base) = hi;
      *(s8v*)(blo + base) = lo;
    }
    return;
  }
  __shared__ s8v Ah[512], Al[512], Bh[512], Bl[512];
  const int mt = blockIdx.x & 31, nt = blockIdx.x >> 5;
  const int tid = threadIdx.x;
  const int lane = tid & 63, wave = tid >> 6;
  const int wm = wave >> 1, wn = wave & 1;
  const int m0 = mt * 128, n0 = nt * 128;
  f4v acc[4][4] = {};

  for (int ks = 0; ks < 16; ++ks) {
    const int k0 = ks * 32;
#pragma unroll
    for (int c = 0; c < 2; ++c) {
      int idx = c * 256 + tid;
      int r = idx >> 2, kg = idx & 3;
      int kgp = kg ^ (r & 3);
      int t_ = tok[m0 + r];
      const float* as = emb + (size_t)t_ * HID + k0 + kg * 8;
      float4 a0 = *(const float4*)as;
      float4 a1 = *(const float4*)(as + 4);
      float av[8] = {a0.x, a0.y, a0.z, a0.w, a1.x, a1.y, a1.z, a1.w};
      s8v ah, al;
#pragma unroll
      for (int j = 0; j < 8; ++j) {
        unsigned short h = f2bf_rne(av[j]);
        ah[j] = (short)h;
        al[j] = (short)f2bf_rne(av[j] - bf2f(h));
      }
      Ah[r * 4 + kgp] = ah;  Al[r * 4 + kgp] = al;
      const float* bs = w1 + (size_t)(n0 + r) * 1024 + k0 + kg * 8;
      float4 b0 = *(const float4*)bs;
      float4 b1v = *(const float4*)(bs + 4);
      float bv[8] = {b0.x, b0.y, b0.z, b0.w, b1v.x, b1v.y, b1v.z, b1v.w};
      s8v bh, bl;
#pragma unroll
      for (int j = 0; j < 8; ++j) {
        unsigned short h = f2bf_rne(bv[j]);
        bh[j] = (short)h;
        bl[j] = (short)f2bf_rne(bv[j] - bf2f(h));
      }
      Bh[r * 4 + kgp] = bh;  Bl[r * 4 + kgp] = bl;
    }
    __syncthreads();
    s8v afh[4], afl[4], bfh[4], bfl[4];
#pragma unroll
    for (int f = 0; f < 4; ++f) {
      int rA = wm * 64 + f * 16 + (lane & 15);
      afh[f] = Ah[rA * 4 + ((lane >> 4) ^ (rA & 3))];
      afl[f] = Al[rA * 4 + ((lane >> 4) ^ (rA & 3))];
      int rB = wn * 64 + f * 16 + (lane & 15);
      bfh[f] = Bh[rB * 4 + ((lane >> 4) ^ (rB & 3))];
      bfl[f] = Bl[rB * 4 + ((lane >> 4) ^ (rB & 3))];
    }
#pragma unroll
    for (int i = 0; i < 4; ++i)
#pragma unroll
      for (int j = 0; j < 4; ++j)
        acc[i][j] = MFMA16(afh[i], bfh[j], acc[i][j]);
#pragma unroll
    for (int i = 0; i < 4; ++i)
#pragma unroll
      for (int j = 0; j < 4; ++j)
        acc[i][j] = MFMA16(afl[i], bfh[j], acc[i][j]);
#pragma unroll
    for (int i = 0; i < 4; ++i)
#pragma unroll
      for (int j = 0; j < 4; ++j)
        acc[i][j] = MFMA16(afh[i], bfl[j], acc[i][j]);
    __syncthreads();
  }
#pragma unroll
  for (int j = 0; j < 4; ++j) {
    int col = n0 + wn * 64 + j * 16 + (lane & 15);
    float bias = b1f[col];
#pragma unroll
    for (int i = 0; i < 4; ++i)
#pragma unroll
      for (int rg = 0; rg < 4; ++rg) {
        int row = m0 + wm * 64 + i * 16 + (lane >> 4) * 4 + rg;
        pre[(size_t)row * HID + col] = acc[i][j][rg] + bias;
      }
  }
}

// ---------------------------------------------------------------------------
// K2: barrier-free persistent scan — round-5 version restored (finish by
// 64 threads, 16 serial padded part reads; 458 us measured).
// ---------------------------------------------------------------------------
__global__ __launch_bounds__(512) void scan_kernel(
    const float* __restrict__ w1, const float* __restrict__ pre,
    unsigned long long* hbuf,
    ushort_t* __restrict__ o_hi, ushort_t* __restrict__ o_lo,
    float* __restrict__ h_last_out) {
  __shared__ float wLds[16384];
  __shared__ float hs[2][512];
  __shared__ float part[2][528];

  const int bp = blockIdx.x & 7;
  const int sg = blockIdx.x >> 3;
  const int b0 = bp * 2, b1 = b0 + 1;
  const int tid = threadIdx.x;

#pragma unroll
  for (int k = 0; k < 8; ++k) {
    int uid = k * 512 + tid;
    int r = uid >> 7, u = uid & 127;
    float4 v = *(const float4*)(w1 + (size_t)(sg * 32 + r) * 1024 + 512 + u * 4);
    int dst = r * 512 + (u >> 3) * 32 + (((u & 7) ^ (r & 7)) << 2);
    *(float4*)(&wLds[dst]) = v;
  }
  __syncthreads();

  const int i = tid & 31, s = tid >> 5;
  const int rowbase = i * 512 + s * 32;
  const int isw = i & 7;

  for (int t = 0; t < T_STEPS; ++t) {
    const int cur = t & 1, nxt = cur ^ 1;

    float pv = 0.f;
    if (tid < 64) {
      int bl = tid >> 5, ii = tid & 31;
      pv = pre[(size_t)(t * BATCH + b0 + bl) * HID + sg * 32 + ii];
    }

    unsigned long long* p0 = hbuf + ((size_t)cur * BATCH + b0) * HID + tid;
    unsigned long long* p1 = hbuf + ((size_t)cur * BATCH + b1) * HID + tid;
    unsigned long long e0 = __hip_atomic_load(p0, __ATOMIC_RELAXED, __HIP_MEMORY_SCOPE_AGENT);
    unsigned long long e1 = __hip_atomic_load(p1, __ATOMIC_RELAXED, __HIP_MEMORY_SCOPE_AGENT);
    int spins = 0;
    while ((unsigned)(e0 >> 32) != (unsigned)t || (unsigned)(e1 >> 32) != (unsigned)t) {
      __builtin_amdgcn_s_sleep(1);
      if ((unsigned)(e0 >> 32) != (unsigned)t)
        e0 = __hip_atomic_load(p0, __ATOMIC_RELAXED, __HIP_MEMORY_SCOPE_AGENT);
      if ((unsigned)(e1 >> 32) != (unsigned)t)
        e1 = __hip_atomic_load(p1, __ATOMIC_RELAXED, __HIP_MEMORY_SCOPE_AGENT);
      if (++spins > (1 << 20)) break;
    }
    hs[0][tid] = __uint_as_float((unsigned)e0);
    hs[1][tid] = __uint_as_float((unsigned)e1);
    __syncthreads();

    float a0 = 0.f, a1 = 0.f;
#pragma unroll
    for (int u = 0; u < 8; ++u) {
      float4 w = *(const float4*)(&wLds[rowbase + ((u ^ isw) << 2)]);
      float4 h0 = *(const float4*)(&hs[0][s * 32 + (u << 2)]);
      float4 h1 = *(const float4*)(&hs[1][s * 32 + (u << 2)]);
      a0 += w.x * h0.x + w.y * h0.y + w.z * h0.z + w.w * h0.w;
      a1 += w.x * h1.x + w.y * h1.y + w.z * h1.z + w.w * h1.w;
    }
    part[0][s * 33 + i] = a0;
    part[1][s * 33 + i] = a1;
    __syncthreads();

    if (tid < 64) {
      int bl = tid >> 5, ii = tid & 31;
      float ssum = 0.f;
#pragma unroll
      for (int ss = 0; ss < 16; ++ss) ssum += part[bl][ss * 33 + ii];
      ssum += pv;
      float hn = tanhf(ssum);
      int b = b0 + bl;
      unsigned long long ev = ((unsigned long long)(unsigned)(t + 1) << 32) |
                              (unsigned long long)__float_as_uint(hn);
      __hip_atomic_store(hbuf + ((size_t)nxt * BATCH + b) * HID + sg * 32 + ii, ev,
                         __ATOMIC_RELAXED, __HIP_MEMORY_SCOPE_AGENT);
      int m = t * BATCH + b;
      int mt = m >> 7, r = m & 127;
      int kg = ii >> 3, e = ii & 7;
      size_t ao = ((size_t)(mt * 16 + sg) * 512 + unit_swz(r, kg)) * 8 + e;
      unsigned short hi_ = f2bf_rne(hn);
      o_hi[ao] = hi_;
      o_lo[ao] = f2bf_rne(hn - bf2f(hi_));
      if (t == T_STEPS - 1) h_last_out[(size_t)b * HID + sg * 32 + ii] = hn;
    }
  }
}

// ---------------------------------------------------------------------------
// K3 v4: 256x256 deep-pipelined decode GEMM, 32x32x16 MFMA shape.
// Same staging / double-buffer / raw-barrier / counted-vmcnt as rounds 5-6;
// only the compute tiling changed: per wave 4x2 tiles of 32x32, 48 MFMA/kt
// (vs 96 at 16x16) -> half the issue slots, 2x FLOP per instruction.
// A/B frag: row = lane&31, k = (lane>>5)*8 + e (family-symmetric mapping).
// C/D: col = lane&31 (B row), row = (reg&3) + 8*(reg>>2) + 4*(lane>>5).
// ---------------------------------------------------------------------------
__global__ __launch_bounds__(512, 2) void dec_gemm_v3(
    const ushort_t* __restrict__ ahi, const ushort_t* __restrict__ alo,
    const ushort_t* __restrict__ bhi, const ushort_t* __restrict__ blo,
    const float* __restrict__ dec_b, float* __restrict__ out) {
  extern __shared__ s8v SB[];   // 2 x 4096 units of 16B
  const int bid = blockIdx.x;
  const int wg  = (bid & 7) * 250 + (bid >> 3);   // XCD-bijective (2000 = 8*250)
  const int mt2 = wg & 15, nt2 = wg >> 4;         // mt fastest: B-panel L2 reuse
  const int tid = threadIdx.x, lane = tid & 63, wv = tid >> 6;
  const int wm = wv >> 2, wn = wv & 3;            // 2 x 4 wave grid
  const int lane32 = lane & 31, kh = lane >> 5;
  const int tB = wn >> 1;

  const ushort_t* gsrc;
  int gtile;
  if (wv < 4) { gsrc = (wv < 2) ? ahi : alo; gtile = mt2 * 2 + (wv & 1); }
  else        { gsrc = (wv < 6) ? bhi : blo; gtile = nt2 * 2 + (wv & 1); }

  f16v acc[4][2] = {};   // [tm][tn] 32x32 tiles; 128 VGPRs

  {
    const char* g0 = (const char*)(gsrc + (size_t)(gtile * 16 + 0) * 4096);
    const char* g1 = (const char*)(gsrc + (size_t)(gtile * 16 + 1) * 4096);
    char* l0 = (char*)SB + wv * 8192;
    char* l1 = (char*)SB + 65536 + wv * 8192;
#pragma unroll
    for (int p = 0; p < 8; ++p) gload16(g0 + p * 1024 + (size_t)lane * 16, l0 + p * 1024);
#pragma unroll
    for (int p = 0; p < 8; ++p) gload16(g1 + p * 1024 + (size_t)lane * 16, l1 + p * 1024);
    asm volatile("s_waitcnt vmcnt(8)" ::: "memory");   // kt0 landed
    __builtin_amdgcn_sched_barrier(0);
    __builtin_amdgcn_s_barrier();
    __builtin_amdgcn_sched_barrier(0);
  }

  for (int kt = 0; kt < KT_DEC; ++kt) {
    const int c = kt & 1;
    const s8v* B0 = SB + c * 4096;

    // B fragments: [tn][s]  (8 x b128)
    s8v bh[2][2], bl[2][2];
#pragma unroll
    for (int tn = 0; tn < 2; ++tn)
#pragma unroll
      for (int s = 0; s < 2; ++s) {
        int rB = (wn & 1) * 64 + tn * 32 + lane32;
        int u = unit_swz(rB, s * 2 + kh);
        bh[tn][s] = B0[(4 + tB) * 512 + u];
        bl[tn][s] = B0[(6 + tB) * 512 + u];
      }
    // A in tm-pairs: 8 frags live; 3 passes of 8 independent MFMAs each
#pragma unroll
    for (int tp = 0; tp < 2; ++tp) {
      const int tm0 = tp * 2, tm1 = tp * 2 + 1;
      s8v a0h[2], a0l[2], a1h[2], a1l[2];
#pragma unroll
      for (int s = 0; s < 2; ++s) {
        int u0 = unit_swz(tm0 * 32 + lane32, s * 2 + kh);
        int u1 = unit_swz(tm1 * 32 + lane32, s * 2 + kh);
        a0h[s] = B0[wm * 512 + u0];
        a0l[s] = B0[1024 + wm * 512 + u0];
        a1h[s] = B0[wm * 512 + u1];
        a1l[s] = B0[1024 + wm * 512 + u1];
      }
      __builtin_amdgcn_s_setprio(1);
      // pass 1: hi*hi   (per-acc distance 4)
#pragma unroll
      for (int s = 0; s < 2; ++s)
#pragma unroll
        for (int tn = 0; tn < 2; ++tn) {
          acc[tm0][tn] = MFMA32(a0h[s], bh[tn][s], acc[tm0][tn]);
          acc[tm1][tn] = MFMA32(a1h[s], bh[tn][s], acc[tm1][tn]);
        }
      // pass 2: lo*hi
#pragma unroll
      for (int s = 0; s < 2; ++s)
#pragma unroll
        for (int tn = 0; tn < 2; ++tn) {
          acc[tm0][tn] = MFMA32(a0l[s], bh[tn][s], acc[tm0][tn]);
          acc[tm1][tn] = MFMA32(a1l[s], bh[tn][s], acc[tm1][tn]);
        }
      // pass 3: hi*lo
#pragma unroll
      for (int s = 0; s < 2; ++s)
#pragma unroll
        for (int tn = 0; tn < 2; ++tn) {
          acc[tm0][tn] = MFMA32(a0h[s], bl[tn][s], acc[tm0][tn]);
          acc[tm1][tn] = MFMA32(a1h[s], bl[tn][s], acc[tm1][tn]);
        }
      __builtin_amdgcn_s_setprio(0);
    }
    asm volatile("s_waitcnt lgkmcnt(0)" ::: "memory");
    __builtin_amdgcn_sched_barrier(0);
    __builtin_amdgcn_s_barrier();           // safe to overwrite buf c
    __builtin_amdgcn_sched_barrier(0);
    if (kt + 2 < KT_DEC) {
      const char* g = (const char*)(gsrc + (size_t)(gtile * 16 + kt + 2) * 4096);
      char* l = (char*)SB + c * 65536 + wv * 8192;
#pragma unroll
      for (int p = 0; p < 8; ++p) gload16(g + p * 1024 + (size_t)lane * 16, l + p * 1024);
      asm volatile("s_waitcnt vmcnt(8)" ::: "memory");   // kt+1 landed
    } else {
      asm volatile("s_waitcnt vmcnt(0)" ::: "memory");   // tail drain
    }
    __builtin_amdgcn_sched_barrier(0);
    __builtin_amdgcn_s_barrier();           // kt+1 visible to all waves
    __builtin_amdgcn_sched_barrier(0);
  }

  const int m0 = mt2 * 256, n0 = nt2 * 256;
#pragma unroll
  for (int tn = 0; tn < 2; ++tn) {
    int col = n0 + wn * 64 + tn * 32 + lane32;
    float bias = dec_b[col];
#pragma unroll
    for (int tm = 0; tm < 4; ++tm) {
      int rowb = m0 + wm * 128 + tm * 32 + 4 * kh;
#pragma unroll
      for (int reg = 0; reg < 16; ++reg) {
        int row = rowb + (reg & 3) + 8 * (reg >> 2);
        out[(size_t)row * VOCAB + col] = acc[tm][tn][reg] + bias;
      }
    }
  }
}

// ---------------------------------------------------------------------------
// K3 fallback (ws too small for presplit): unchanged.
// ---------------------------------------------------------------------------
__global__ __launch_bounds__(256, 2) void dec_gemm_fb(
    const ushort_t* __restrict__ o_hi, const ushort_t* __restrict__ o_lo,
    const float* __restrict__ dec_w, const float* __restrict__ dec_b,
    float* __restrict__ out) {
  __shared__ s8v Ah[512], Al[512], Bh[512], Bl[512];
  const int mt = blockIdx.x, nt = blockIdx.y;
  const int tid = threadIdx.x;
  const int lane = tid & 63, wave = tid >> 6;
  const int wm = wave >> 1, wn = wave & 1;
  const int kgl = lane >> 4, lr = lane & 15;
  const int m0 = mt * 128, n0 = nt * 128;
  f4v acc[4][4] = {};

  for (int ks = 0; ks < KT_DEC; ++ks) {
    const int k0 = ks * 32;
#pragma unroll
    for (int c = 0; c < 2; ++c) {
      int idx = c * 256 + tid;
      size_t abase = (size_t)(mt * 16 + ks) * 4096 + (size_t)idx * 8;
      Ah[idx] = *(const s8v*)(o_hi + abase);
      Al[idx] = *(const s8v*)(o_lo + abase);
      int r = idx >> 2, kg = idx & 3;
      const float* bs = dec_w + (size_t)(n0 + r) * HID + k0 + kg * 8;
      float4 b0 = *(const float4*)bs;
      float4 b1v = *(const float4*)(bs + 4);
      float bv[8] = {b0.x, b0.y, b0.z, b0.w, b1v.x, b1v.y, b1v.z, b1v.w};
      s8v bh, bl;
#pragma unroll
      for (int j = 0; j < 8; ++j) {
        unsigned short h = f2bf_rne(bv[j]);
        bh[j] = (short)h;
        bl[j] = (short)f2bf_rne(bv[j] - bf2f(h));
      }
      int ub = unit_swz(r, kg);
      Bh[ub] = bh;  Bl[ub] = bl;
    }
    __syncthreads();
    s8v afh[4], afl[4], bfh[4], bfl[4];
#pragma unroll
    for (int f = 0; f < 4; ++f) {
      int rA = wm * 64 + f * 16 + lr;
      int uA = unit_swz(rA, kgl);
      afh[f] = Ah[uA];  afl[f] = Al[uA];
      int rB = wn * 64 + f * 16 + lr;
      int uB = unit_swz(rB, kgl);
      bfh[f] = Bh[uB];  bfl[f] = Bl[uB];
    }
#pragma unroll
    for (int i = 0; i < 4; ++i)
#pragma unroll
      for (int j = 0; j < 4; ++j)
        acc[i][j] = MFMA16(afh[i], bfh[j], acc[i][j]);
#pragma unroll
    for (int i = 0; i < 4; ++i)
#pragma unroll
      for (int j = 0; j < 4; ++j)
        acc[i][j] = MFMA16(afl[i], bfh[j], acc[i][j]);
#pragma unroll
    for (int i = 0; i < 4; ++i)
#pragma unroll
      for (int j = 0; j < 4; ++j)
        acc[i][j] = MFMA16(afh[i], bfl[j], acc[i][j]);
    __syncthreads();
  }
#pragma unroll
  for (int j = 0; j < 4; ++j) {
    int col = n0 + wn * 64 + j * 16 + lr;
    float bias = dec_b[col];
#pragma unroll
    for (int i = 0; i < 4; ++i)
#pragma unroll
      for (int rg = 0; rg < 4; ++rg) {
        int row = m0 + wm * 64 + i * 16 + (lane >> 4) * 4 + rg;
        out[(size_t)row * VOCAB + col] = acc[i][j][rg] + bias;
      }
  }
}

// ---------------------------------------------------------------------------
// Workspace layout (bytes):
//   [0,       128 KiB)   hbuf: u64[2][16][512] (tag|f32)  (zeroed each call)
//   [1 MiB,    9 MiB)    pre : 4096 x 512 f32
//   [16 MiB,  20 MiB)    o_hi: tile-ready A hi (32x16 tiles x 8 KiB)
//   [20 MiB,  24 MiB)    o_lo: tile-ready A lo
//   [24 MiB,  ~55 MiB)   bhi : tile-ready dec_w hi (250x16 tiles x 8 KiB)
//   [56 MiB,  ~87 MiB)   blo : tile-ready dec_w lo
// ---------------------------------------------------------------------------
extern "C" void kernel_launch(void* const* d_in, const int* in_sizes, int n_in,
                              void* d_out, int out_size, void* d_ws, size_t ws_size,
                              hipStream_t stream) {
  (void)in_sizes; (void)n_in; (void)out_size;
  const int*   tok   = (const int*)d_in[0];
  const float* emb   = (const float*)d_in[2];
  const float* w1    = (const float*)d_in[3];
  const float* b1    = (const float*)d_in[4];
  const float* dec_w = (const float*)d_in[5];
  const float* dec_b = (const float*)d_in[6];
  char* ws = (char*)d_ws;
  unsigned long long* hbuf = (unsigned long long*)(ws);
  float* pre  = (float*)(ws + (1u << 20));
  ushort_t* o_hi = (ushort_t*)(ws + 16u * (1u << 20));
  ushort_t* o_lo = (ushort_t*)(ws + 20u * (1u << 20));
  ushort_t* bhi  = (ushort_t*)(ws + 24u * (1u << 20));
  ushort_t* blo  = (ushort_t*)(ws + 56u * (1u << 20));
  float* out = (float*)d_out;

  const int big = (ws_size >= (size_t)92 * 1024 * 1024) ? 1 : 0;

  hipMemsetAsync(ws, 0, 131072, stream);   // tag=0, h0=0
  head_kernel<<<dim3(4128), dim3(256), 0, stream>>>(
      tok, emb, w1, b1, pre, dec_w, bhi, blo, big);
  scan_kernel<<<dim3(128), dim3(512), 0, stream>>>(
      w1, pre, hbuf, o_hi, o_lo, out + (size_t)M_TOT * VOCAB);
  if (big) {
    hipFuncSetAttribute((const void*)dec_gemm_v3,
                        hipFuncAttributeMaxDynamicSharedMemorySize, 131072);
    dec_gemm_v3<<<dim3(2000), dim3(512), 131072, stream>>>(
        o_hi, o_lo, bhi, blo, dec_b, out);
  } else {
    dec_gemm_fb<<<dim3(32, 250), dim3(256), 0, stream>>>(o_hi, o_lo, dec_w, dec_b, out);
  }
}

// Round 8
// 911.068 us; speedup vs baseline: 1.1346x; 1.0184x over previous
//
#include <hip/hip_runtime.h>
#include <hip/hip_bf16.h>

// Problem constants (fixed by reference)
#define T_STEPS 256
#define BATCH   16
#define HID     512
#define VOCAB   32000
#define M_TOT   (T_STEPS * BATCH)   // 4096
#define KT_DEC  16                  // 512/32

typedef __attribute__((ext_vector_type(8))) short s8v;    // 8 bf16 (4 VGPRs)
typedef __attribute__((ext_vector_type(4))) float f4v;    // 4 f32 accum
typedef __attribute__((ext_vector_type(16))) float f16v;  // 16 f32 accum (32x32)
typedef unsigned short ushort_t;

__device__ __forceinline__ unsigned short f2bf_rne(float f) {
  unsigned u = __float_as_uint(f);
  unsigned r = u + 0x7fffu + ((u >> 16) & 1u);
  return (unsigned short)(r >> 16);
}
__device__ __forceinline__ float bf2f(unsigned short s) {
  return __uint_as_float(((unsigned)s) << 16);
}
// Tile unit layout: tile = [128 rows r][4 k-groups kg] of s8v (16B) units.
__device__ __forceinline__ int unit_swz(int r, int kg) {
  return r * 4 + (kg ^ ((r >> 1) & 3));
}
// async global->LDS, 16B/lane; LDS dest = wave-uniform base + lane*16 (HW)
__device__ __forceinline__ void gload16(const void* g, void* l) {
  __builtin_amdgcn_global_load_lds(
      (const __attribute__((address_space(1))) unsigned int*)g,
      (__attribute__((address_space(3))) unsigned int*)l, 16, 0, 0);
}
#define MFMA16(a, b, c) __builtin_amdgcn_mfma_f32_16x16x32_bf16((a), (b), (c), 0, 0, 0)
#define MFMA32(a, b, c) __builtin_amdgcn_mfma_f32_32x32x16_bf16((a), (b), (c), 0, 0, 0)

// ---------------------------------------------------------------------------
// K1 "head": blocks 0..127  = pre-GEMM; blocks 128..4127 = dec_w presplit.
// (unchanged)
// ---------------------------------------------------------------------------
__global__ __launch_bounds__(256, 2) void head_kernel(
    const int* __restrict__ tok, const float* __restrict__ emb,
    const float* __restrict__ w1, const float* __restrict__ b1f,
    float* __restrict__ pre,
    const float* __restrict__ dec_w, ushort_t* __restrict__ bhi,
    ushort_t* __restrict__ blo, int do_split) {
  if (blockIdx.x >= 128) {
    if (!do_split) return;
    const int pid = blockIdx.x - 128;
    const int nt = pid >> 4, ks = pid & 15;
    const int tid = threadIdx.x;
#pragma unroll
    for (int h = 0; h < 2; ++h) {
      int us = h * 256 + tid;
      int r = us >> 2, kg = us & 3;
      const float* src = dec_w + (size_t)(nt * 128 + r) * HID + ks * 32 + kg * 8;
      float4 v0 = *(const float4*)src;
      float4 v1 = *(const float4*)(src + 4);
      float av[8] = {v0.x, v0.y, v0.z, v0.w, v1.x, v1.y, v1.z, v1.w};
      s8v hi, lo;
#pragma unroll
      for (int j = 0; j < 8; ++j) {
        unsigned short hh = f2bf_rne(av[j]);
        hi[j] = (short)hh;
        lo[j] = (short)f2bf_rne(av[j] - bf2f(hh));
      }
      size_t base = ((size_t)(nt * 16 + ks) * 512 + unit_swz(r, kg)) * 8;
      *(s8v*)(bhi + base) = hi;
      *(s8v*)(blo + base) = lo;
    }
    return;
  }
  __shared__ s8v Ah[512], Al[512], Bh[512], Bl[512];
  const int mt = blockIdx.x & 31, nt = blockIdx.x >> 5;
  const int tid = threadIdx.x;
  const int lane = tid & 63, wave = tid >> 6;
  const int wm = wave >> 1, wn = wave & 1;
  const int m0 = mt * 128, n0 = nt * 128;
  f4v acc[4][4] = {};

  for (int ks = 0; ks < 16; ++ks) {
    const int k0 = ks * 32;
#pragma unroll
    for (int c = 0; c < 2; ++c) {
      int idx = c * 256 + tid;
      int r = idx >> 2, kg = idx & 3;
      int kgp = kg ^ (r & 3);
      int t_ = tok[m0 + r];
      const float* as = emb + (size_t)t_ * HID + k0 + kg * 8;
      float4 a0 = *(const float4*)as;
      float4 a1 = *(const float4*)(as + 4);
      float av[8] = {a0.x, a0.y, a0.z, a0.w, a1.x, a1.y, a1.z, a1.w};
      s8v ah, al;
#pragma unroll
      for (int j = 0; j < 8; ++j) {
        unsigned short h = f2bf_rne(av[j]);
        ah[j] = (short)h;
        al[j] = (short)f2bf_rne(av[j] - bf2f(h));
      }
      Ah[r * 4 + kgp] = ah;  Al[r * 4 + kgp] = al;
      const float* bs = w1 + (size_t)(n0 + r) * 1024 + k0 + kg * 8;
      float4 b0 = *(const float4*)bs;
      float4 b1v = *(const float4*)(bs + 4);
      float bv[8] = {b0.x, b0.y, b0.z, b0.w, b1v.x, b1v.y, b1v.z, b1v.w};
      s8v bh, bl;
#pragma unroll
      for (int j = 0; j < 8; ++j) {
        unsigned short h = f2bf_rne(bv[j]);
        bh[j] = (short)h;
        bl[j] = (short)f2bf_rne(bv[j] - bf2f(h));
      }
      Bh[r * 4 + kgp] = bh;  Bl[r * 4 + kgp] = bl;
    }
    __syncthreads();
    s8v afh[4], afl[4], bfh[4], bfl[4];
#pragma unroll
    for (int f = 0; f < 4; ++f) {
      int rA = wm * 64 + f * 16 + (lane & 15);
      afh[f] = Ah[rA * 4 + ((lane >> 4) ^ (rA & 3))];
      afl[f] = Al[rA * 4 + ((lane >> 4) ^ (rA & 3))];
      int rB = wn * 64 + f * 16 + (lane & 15);
      bfh[f] = Bh[rB * 4 + ((lane >> 4) ^ (rB & 3))];
      bfl[f] = Bl[rB * 4 + ((lane >> 4) ^ (rB & 3))];
    }
#pragma unroll
    for (int i = 0; i < 4; ++i)
#pragma unroll
      for (int j = 0; j < 4; ++j)
        acc[i][j] = MFMA16(afh[i], bfh[j], acc[i][j]);
#pragma unroll
    for (int i = 0; i < 4; ++i)
#pragma unroll
      for (int j = 0; j < 4; ++j)
        acc[i][j] = MFMA16(afl[i], bfh[j], acc[i][j]);
#pragma unroll
    for (int i = 0; i < 4; ++i)
#pragma unroll
      for (int j = 0; j < 4; ++j)
        acc[i][j] = MFMA16(afh[i], bfl[j], acc[i][j]);
    __syncthreads();
  }
#pragma unroll
  for (int j = 0; j < 4; ++j) {
    int col = n0 + wn * 64 + j * 16 + (lane & 15);
    float bias = b1f[col];
#pragma unroll
    for (int i = 0; i < 4; ++i)
#pragma unroll
      for (int rg = 0; rg < 4; ++rg) {
        int row = m0 + wm * 64 + i * 16 + (lane >> 4) * 4 + rg;
        pre[(size_t)row * HID + col] = acc[i][j][rg] + bias;
      }
  }
}

// ---------------------------------------------------------------------------
// K2: barrier-free persistent scan (round-5 version, 459 us measured).
// ---------------------------------------------------------------------------
__global__ __launch_bounds__(512) void scan_kernel(
    const float* __restrict__ w1, const float* __restrict__ pre,
    unsigned long long* hbuf,
    ushort_t* __restrict__ o_hi, ushort_t* __restrict__ o_lo,
    float* __restrict__ h_last_out) {
  __shared__ float wLds[16384];
  __shared__ float hs[2][512];
  __shared__ float part[2][528];

  const int bp = blockIdx.x & 7;
  const int sg = blockIdx.x >> 3;
  const int b0 = bp * 2, b1 = b0 + 1;
  const int tid = threadIdx.x;

#pragma unroll
  for (int k = 0; k < 8; ++k) {
    int uid = k * 512 + tid;
    int r = uid >> 7, u = uid & 127;
    float4 v = *(const float4*)(w1 + (size_t)(sg * 32 + r) * 1024 + 512 + u * 4);
    int dst = r * 512 + (u >> 3) * 32 + (((u & 7) ^ (r & 7)) << 2);
    *(float4*)(&wLds[dst]) = v;
  }
  __syncthreads();

  const int i = tid & 31, s = tid >> 5;
  const int rowbase = i * 512 + s * 32;
  const int isw = i & 7;

  for (int t = 0; t < T_STEPS; ++t) {
    const int cur = t & 1, nxt = cur ^ 1;

    float pv = 0.f;
    if (tid < 64) {
      int bl = tid >> 5, ii = tid & 31;
      pv = pre[(size_t)(t * BATCH + b0 + bl) * HID + sg * 32 + ii];
    }

    unsigned long long* p0 = hbuf + ((size_t)cur * BATCH + b0) * HID + tid;
    unsigned long long* p1 = hbuf + ((size_t)cur * BATCH + b1) * HID + tid;
    unsigned long long e0 = __hip_atomic_load(p0, __ATOMIC_RELAXED, __HIP_MEMORY_SCOPE_AGENT);
    unsigned long long e1 = __hip_atomic_load(p1, __ATOMIC_RELAXED, __HIP_MEMORY_SCOPE_AGENT);
    int spins = 0;
    while ((unsigned)(e0 >> 32) != (unsigned)t || (unsigned)(e1 >> 32) != (unsigned)t) {
      __builtin_amdgcn_s_sleep(1);
      if ((unsigned)(e0 >> 32) != (unsigned)t)
        e0 = __hip_atomic_load(p0, __ATOMIC_RELAXED, __HIP_MEMORY_SCOPE_AGENT);
      if ((unsigned)(e1 >> 32) != (unsigned)t)
        e1 = __hip_atomic_load(p1, __ATOMIC_RELAXED, __HIP_MEMORY_SCOPE_AGENT);
      if (++spins > (1 << 20)) break;
    }
    hs[0][tid] = __uint_as_float((unsigned)e0);
    hs[1][tid] = __uint_as_float((unsigned)e1);
    __syncthreads();

    float a0 = 0.f, a1 = 0.f;
#pragma unroll
    for (int u = 0; u < 8; ++u) {
      float4 w = *(const float4*)(&wLds[rowbase + ((u ^ isw) << 2)]);
      float4 h0 = *(const float4*)(&hs[0][s * 32 + (u << 2)]);
      float4 h1 = *(const float4*)(&hs[1][s * 32 + (u << 2)]);
      a0 += w.x * h0.x + w.y * h0.y + w.z * h0.z + w.w * h0.w;
      a1 += w.x * h1.x + w.y * h1.y + w.z * h1.z + w.w * h1.w;
    }
    part[0][s * 33 + i] = a0;
    part[1][s * 33 + i] = a1;
    __syncthreads();

    if (tid < 64) {
      int bl = tid >> 5, ii = tid & 31;
      float ssum = 0.f;
#pragma unroll
      for (int ss = 0; ss < 16; ++ss) ssum += part[bl][ss * 33 + ii];
      ssum += pv;
      float hn = tanhf(ssum);
      int b = b0 + bl;
      unsigned long long ev = ((unsigned long long)(unsigned)(t + 1) << 32) |
                              (unsigned long long)__float_as_uint(hn);
      __hip_atomic_store(hbuf + ((size_t)nxt * BATCH + b) * HID + sg * 32 + ii, ev,
                         __ATOMIC_RELAXED, __HIP_MEMORY_SCOPE_AGENT);
      int m = t * BATCH + b;
      int mt = m >> 7, r = m & 127;
      int kg = ii >> 3, e = ii & 7;
      size_t ao = ((size_t)(mt * 16 + sg) * 512 + unit_swz(r, kg)) * 8 + e;
      unsigned short hi_ = f2bf_rne(hn);
      o_hi[ao] = hi_;
      o_lo[ao] = f2bf_rne(hn - bf2f(hi_));
      if (t == T_STEPS - 1) h_last_out[(size_t)b * HID + sg * 32 + ii] = hn;
    }
  }
}

// ---------------------------------------------------------------------------
// K3 v5: 256x256 decode GEMM, 32x32x16, intra-kt software pipeline:
//   issue 24 ds_reads (16 then 8) -> lgkm(8) -> cluster0 (24 MFMA, tm0/1)
//   -> lgkm(0) -> bar -> issue stage kt+2 -> cluster1 (24 MFMA, tm2/3)
//   -> vmcnt(8) -> bar.
// Group2 reads hide under cluster0; stage + barrier window hides under
// cluster1. Per-acc op order identical to rounds 5-7 (bit-identical output).
// ---------------------------------------------------------------------------
__global__ __launch_bounds__(512, 2) void dec_gemm_v3(
    const ushort_t* __restrict__ ahi, const ushort_t* __restrict__ alo,
    const ushort_t* __restrict__ bhi, const ushort_t* __restrict__ blo,
    const float* __restrict__ dec_b, float* __restrict__ out) {
  extern __shared__ s8v SB[];   // 2 x 4096 units of 16B
  const int bid = blockIdx.x;
  const int wg  = (bid & 7) * 250 + (bid >> 3);   // XCD-bijective (2000 = 8*250)
  const int mt2 = wg & 15, nt2 = wg >> 4;         // mt fastest: B-panel L2 reuse
  const int tid = threadIdx.x, lane = tid & 63, wv = tid >> 6;
  const int wm = wv >> 2, wn = wv & 3;            // 2 x 4 wave grid
  const int lane32 = lane & 31, kh = lane >> 5;
  const int tB = wn >> 1;

  const ushort_t* gsrc;
  int gtile;
  if (wv < 4) { gsrc = (wv < 2) ? ahi : alo; gtile = mt2 * 2 + (wv & 1); }
  else        { gsrc = (wv < 6) ? bhi : blo; gtile = nt2 * 2 + (wv & 1); }

  // precomputed LDS unit indices (constant across kt; lo image = +1024)
  int uB_[2][2], uA_[4][2];
#pragma unroll
  for (int tn = 0; tn < 2; ++tn)
#pragma unroll
    for (int s = 0; s < 2; ++s)
      uB_[tn][s] = (4 + tB) * 512 +
                   unit_swz((wn & 1) * 64 + tn * 32 + lane32, s * 2 + kh);
#pragma unroll
  for (int tm = 0; tm < 4; ++tm)
#pragma unroll
    for (int s = 0; s < 2; ++s)
      uA_[tm][s] = wm * 512 + unit_swz(tm * 32 + lane32, s * 2 + kh);

  f16v acc[4][2] = {};   // [tm][tn] 32x32 tiles; 128 VGPRs

  // ---- prologue: stage kt=0 -> buf0, kt=1 -> buf1 ----
  {
    const char* g0 = (const char*)(gsrc + (size_t)(gtile * 16 + 0) * 4096);
    const char* g1 = (const char*)(gsrc + (size_t)(gtile * 16 + 1) * 4096);
    char* l0 = (char*)SB + wv * 8192;
    char* l1 = (char*)SB + 65536 + wv * 8192;
#pragma unroll
    for (int p = 0; p < 8; ++p) gload16(g0 + p * 1024 + (size_t)lane * 16, l0 + p * 1024);
#pragma unroll
    for (int p = 0; p < 8; ++p) gload16(g1 + p * 1024 + (size_t)lane * 16, l1 + p * 1024);
    asm volatile("s_waitcnt vmcnt(8)" ::: "memory");   // kt0 landed
    __builtin_amdgcn_sched_barrier(0);
    __builtin_amdgcn_s_barrier();
    __builtin_amdgcn_sched_barrier(0);
  }

  for (int kt = 0; kt < KT_DEC; ++kt) {
    const int c = kt & 1;
    const s8v* B0 = SB + c * 4096;

    s8v bh[2][2], bl[2][2], ah[4][2], al[4][2];
    // group 1: B (8) + A tm0/1 (8)
#pragma unroll
    for (int tn = 0; tn < 2; ++tn)
#pragma unroll
      for (int s = 0; s < 2; ++s) {
        bh[tn][s] = B0[uB_[tn][s]];
        bl[tn][s] = B0[1024 + uB_[tn][s]];
      }
#pragma unroll
    for (int tm = 0; tm < 2; ++tm)
#pragma unroll
      for (int s = 0; s < 2; ++s) {
        ah[tm][s] = B0[uA_[tm][s]];
        al[tm][s] = B0[1024 + uA_[tm][s]];
      }
    __builtin_amdgcn_sched_barrier(0);   // group1 emitted before group2
    // group 2: A tm2/3 (8) — completes under cluster0
#pragma unroll
    for (int tm = 2; tm < 4; ++tm)
#pragma unroll
      for (int s = 0; s < 2; ++s) {
        ah[tm][s] = B0[uA_[tm][s]];
        al[tm][s] = B0[1024 + uA_[tm][s]];
      }
    asm volatile("s_waitcnt lgkmcnt(8)" ::: "memory");  // group1 ready
    __builtin_amdgcn_sched_barrier(0);

    __builtin_amdgcn_s_setprio(1);
    // cluster 0: tm0/1 — per-acc order: s0 hh, s1 hh, s0 lh, s1 lh, s0 hl, s1 hl
#pragma unroll
    for (int s = 0; s < 2; ++s)
#pragma unroll
      for (int tn = 0; tn < 2; ++tn) {
        acc[0][tn] = MFMA32(ah[0][s], bh[tn][s], acc[0][tn]);
        acc[1][tn] = MFMA32(ah[1][s], bh[tn][s], acc[1][tn]);
      }
#pragma unroll
    for (int s = 0; s < 2; ++s)
#pragma unroll
      for (int tn = 0; tn < 2; ++tn) {
        acc[0][tn] = MFMA32(al[0][s], bh[tn][s], acc[0][tn]);
        acc[1][tn] = MFMA32(al[1][s], bh[tn][s], acc[1][tn]);
      }
#pragma unroll
    for (int s = 0; s < 2; ++s)
#pragma unroll
      for (int tn = 0; tn < 2; ++tn) {
        acc[0][tn] = MFMA32(ah[0][s], bl[tn][s], acc[0][tn]);
        acc[1][tn] = MFMA32(ah[1][s], bl[tn][s], acc[1][tn]);
      }
    __builtin_amdgcn_s_setprio(0);

    asm volatile("s_waitcnt lgkmcnt(0)" ::: "memory");  // all buf-c reads done
    __builtin_amdgcn_sched_barrier(0);
    __builtin_amdgcn_s_barrier();          // buf c free for overwrite
    __builtin_amdgcn_sched_barrier(0);
    if (kt + 2 < KT_DEC) {                 // stage kt+2 -> buf c (hides under cluster1)
      const char* g = (const char*)(gsrc + (size_t)(gtile * 16 + kt + 2) * 4096);
      char* l = (char*)SB + c * 65536 + wv * 8192;
#pragma unroll
      for (int p = 0; p < 8; ++p) gload16(g + p * 1024 + (size_t)lane * 16, l + p * 1024);
    }
    __builtin_amdgcn_sched_barrier(0);     // stage issued before cluster1

    __builtin_amdgcn_s_setprio(1);
    // cluster 1: tm2/3
#pragma unroll
    for (int s = 0; s < 2; ++s)
#pragma unroll
      for (int tn = 0; tn < 2; ++tn) {
        acc[2][tn] = MFMA32(ah[2][s], bh[tn][s], acc[2][tn]);
        acc[3][tn] = MFMA32(ah[3][s], bh[tn][s], acc[3][tn]);
      }
#pragma unroll
    for (int s = 0; s < 2; ++s)
#pragma unroll
      for (int tn = 0; tn < 2; ++tn) {
        acc[2][tn] = MFMA32(al[2][s], bh[tn][s], acc[2][tn]);
        acc[3][tn] = MFMA32(al[3][s], bh[tn][s], acc[3][tn]);
      }
#pragma unroll
    for (int s = 0; s < 2; ++s)
#pragma unroll
      for (int tn = 0; tn < 2; ++tn) {
        acc[2][tn] = MFMA32(ah[2][s], bl[tn][s], acc[2][tn]);
        acc[3][tn] = MFMA32(ah[3][s], bl[tn][s], acc[3][tn]);
      }
    __builtin_amdgcn_s_setprio(0);

    if (kt + 2 < KT_DEC) {
      asm volatile("s_waitcnt vmcnt(8)" ::: "memory");  // kt+1 landed
    } else {
      asm volatile("s_waitcnt vmcnt(0)" ::: "memory");  // tail drain
    }
    __builtin_amdgcn_sched_barrier(0);
    __builtin_amdgcn_s_barrier();          // kt+1 visible to all waves
    __builtin_amdgcn_sched_barrier(0);
  }

  const int m0 = mt2 * 256, n0 = nt2 * 256;
#pragma unroll
  for (int tn = 0; tn < 2; ++tn) {
    int col = n0 + wn * 64 + tn * 32 + lane32;
    float bias = dec_b[col];
#pragma unroll
    for (int tm = 0; tm < 4; ++tm) {
      int rowb = m0 + wm * 128 + tm * 32 + 4 * kh;
#pragma unroll
      for (int reg = 0; reg < 16; ++reg) {
        int row = rowb + (reg & 3) + 8 * (reg >> 2);
        out[(size_t)row * VOCAB + col] = acc[tm][tn][reg] + bias;
      }
    }
  }
}

// ---------------------------------------------------------------------------
// K3 fallback (ws too small for presplit): unchanged.
// ---------------------------------------------------------------------------
__global__ __launch_bounds__(256, 2) void dec_gemm_fb(
    const ushort_t* __restrict__ o_hi, const ushort_t* __restrict__ o_lo,
    const float* __restrict__ dec_w, const float* __restrict__ dec_b,
    float* __restrict__ out) {
  __shared__ s8v Ah[512], Al[512], Bh[512], Bl[512];
  const int mt = blockIdx.x, nt = blockIdx.y;
  const int tid = threadIdx.x;
  const int lane = tid & 63, wave = tid >> 6;
  const int wm = wave >> 1, wn = wave & 1;
  const int kgl = lane >> 4, lr = lane & 15;
  const int m0 = mt * 128, n0 = nt * 128;
  f4v acc[4][4] = {};

  for (int ks = 0; ks < KT_DEC; ++ks) {
    const int k0 = ks * 32;
#pragma unroll
    for (int c = 0; c < 2; ++c) {
      int idx = c * 256 + tid;
      size_t abase = (size_t)(mt * 16 + ks) * 4096 + (size_t)idx * 8;
      Ah[idx] = *(const s8v*)(o_hi + abase);
      Al[idx] = *(const s8v*)(o_lo + abase);
      int r = idx >> 2, kg = idx & 3;
      const float* bs = dec_w + (size_t)(n0 + r) * HID + k0 + kg * 8;
      float4 b0 = *(const float4*)bs;
      float4 b1v = *(const float4*)(bs + 4);
      float bv[8] = {b0.x, b0.y, b0.z, b0.w, b1v.x, b1v.y, b1v.z, b1v.w};
      s8v bh, bl;
#pragma unroll
      for (int j = 0; j < 8; ++j) {
        unsigned short h = f2bf_rne(bv[j]);
        bh[j] = (short)h;
        bl[j] = (short)f2bf_rne(bv[j] - bf2f(h));
      }
      int ub = unit_swz(r, kg);
      Bh[ub] = bh;  Bl[ub] = bl;
    }
    __syncthreads();
    s8v afh[4], afl[4], bfh[4], bfl[4];
#pragma unroll
    for (int f = 0; f < 4; ++f) {
      int rA = wm * 64 + f * 16 + lr;
      int uA = unit_swz(rA, kgl);
      afh[f] = Ah[uA];  afl[f] = Al[uA];
      int rB = wn * 64 + f * 16 + lr;
      int uB = unit_swz(rB, kgl);
      bfh[f] = Bh[uB];  bfl[f] = Bl[uB];
    }
#pragma unroll
    for (int i = 0; i < 4; ++i)
#pragma unroll
      for (int j = 0; j < 4; ++j)
        acc[i][j] = MFMA16(afh[i], bfh[j], acc[i][j]);
#pragma unroll
    for (int i = 0; i < 4; ++i)
#pragma unroll
      for (int j = 0; j < 4; ++j)
        acc[i][j] = MFMA16(afl[i], bfh[j], acc[i][j]);
#pragma unroll
    for (int i = 0; i < 4; ++i)
#pragma unroll
      for (int j = 0; j < 4; ++j)
        acc[i][j] = MFMA16(afh[i], bfl[j], acc[i][j]);
    __syncthreads();
  }
#pragma unroll
  for (int j = 0; j < 4; ++j) {
    int col = n0 + wn * 64 + j * 16 + lr;
    float bias = dec_b[col];
#pragma unroll
    for (int i = 0; i < 4; ++i)
#pragma unroll
      for (int rg = 0; rg < 4; ++rg) {
        int row = m0 + wm * 64 + i * 16 + (lane >> 4) * 4 + rg;
        out[(size_t)row * VOCAB + col] = acc[i][j][rg] + bias;
      }
  }
}

// ---------------------------------------------------------------------------
// Workspace layout (bytes):
//   [0,       128 KiB)   hbuf: u64[2][16][512] (tag|f32)  (zeroed each call)
//   [1 MiB,    9 MiB)    pre : 4096 x 512 f32
//   [16 MiB,  20 MiB)    o_hi: tile-ready A hi (32x16 tiles x 8 KiB)
//   [20 MiB,  24 MiB)    o_lo: tile-ready A lo
//   [24 MiB,  ~55 MiB)   bhi : tile-ready dec_w hi (250x16 tiles x 8 KiB)
//   [56 MiB,  ~87 MiB)   blo : tile-ready dec_w lo
// ---------------------------------------------------------------------------
extern "C" void kernel_launch(void* const* d_in, const int* in_sizes, int n_in,
                              void* d_out, int out_size, void* d_ws, size_t ws_size,
                              hipStream_t stream) {
  (void)in_sizes; (void)n_in; (void)out_size;
  const int*   tok   = (const int*)d_in[0];
  const float* emb   = (const float*)d_in[2];
  const float* w1    = (const float*)d_in[3];
  const float* b1    = (const float*)d_in[4];
  const float* dec_w = (const float*)d_in[5];
  const float* dec_b = (const float*)d_in[6];
  char* ws = (char*)d_ws;
  unsigned long long* hbuf = (unsigned long long*)(ws);
  float* pre  = (float*)(ws + (1u << 20));
  ushort_t* o_hi = (ushort_t*)(ws + 16u * (1u << 20));
  ushort_t* o_lo = (ushort_t*)(ws + 20u * (1u << 20));
  ushort_t* bhi  = (ushort_t*)(ws + 24u * (1u << 20));
  ushort_t* blo  = (ushort_t*)(ws + 56u * (1u << 20));
  float* out = (float*)d_out;

  const int big = (ws_size >= (size_t)92 * 1024 * 1024) ? 1 : 0;

  hipMemsetAsync(ws, 0, 131072, stream);   // tag=0, h0=0
  head_kernel<<<dim3(4128), dim3(256), 0, stream>>>(
      tok, emb, w1, b1, pre, dec_w, bhi, blo, big);
  scan_kernel<<<dim3(128), dim3(512), 0, stream>>>(
      w1, pre, hbuf, o_hi, o_lo, out + (size_t)M_TOT * VOCAB);
  if (big) {
    hipFuncSetAttribute((const void*)dec_gemm_v3,
                        hipFuncAttributeMaxDynamicSharedMemorySize, 131072);
    dec_gemm_v3<<<dim3(2000), dim3(512), 131072, stream>>>(
        o_hi, o_lo, bhi, blo, dec_b, out);
  } else {
    dec_gemm_fb<<<dim3(32, 250), dim3(256), 0, stream>>>(o_hi, o_lo, dec_w, dec_b, out);
  }
}

// Round 9
// 874.640 us; speedup vs baseline: 1.1819x; 1.0416x over previous
//
#include <hip/hip_runtime.h>
#include <hip/hip_bf16.h>

// Problem constants (fixed by reference)
#define T_STEPS 256
#define BATCH   16
#define HID     512
#define VOCAB   32000
#define M_TOT   (T_STEPS * BATCH)   // 4096
#define KT_DEC  16                  // 512/32

typedef __attribute__((ext_vector_type(8))) short s8v;    // 8 bf16 (4 VGPRs)
typedef __attribute__((ext_vector_type(4))) float f4v;    // 4 f32 accum
typedef __attribute__((ext_vector_type(16))) float f16v;  // 16 f32 accum (32x32)
typedef unsigned short ushort_t;

__device__ __forceinline__ unsigned short f2bf_rne(float f) {
  unsigned u = __float_as_uint(f);
  unsigned r = u + 0x7fffu + ((u >> 16) & 1u);
  return (unsigned short)(r >> 16);
}
__device__ __forceinline__ float bf2f(unsigned short s) {
  return __uint_as_float(((unsigned)s) << 16);
}
// Tile unit layout: tile = [128 rows r][4 k-groups kg] of s8v (16B) units.
__device__ __forceinline__ int unit_swz(int r, int kg) {
  return r * 4 + (kg ^ ((r >> 1) & 3));
}
// async global->LDS, 16B/lane; LDS dest = wave-uniform base + lane*16 (HW)
__device__ __forceinline__ void gload16(const void* g, void* l) {
  __builtin_amdgcn_global_load_lds(
      (const __attribute__((address_space(1))) unsigned int*)g,
      (__attribute__((address_space(3))) unsigned int*)l, 16, 0, 0);
}
#define MFMA16(a, b, c) __builtin_amdgcn_mfma_f32_16x16x32_bf16((a), (b), (c), 0, 0, 0)
#define MFMA32(a, b, c) __builtin_amdgcn_mfma_f32_32x32x16_bf16((a), (b), (c), 0, 0, 0)

// ---------------------------------------------------------------------------
// K1 "head": blocks 0..127  = pre-GEMM; blocks 128..4127 = dec_w presplit.
// (unchanged)
// ---------------------------------------------------------------------------
__global__ __launch_bounds__(256, 2) void head_kernel(
    const int* __restrict__ tok, const float* __restrict__ emb,
    const float* __restrict__ w1, const float* __restrict__ b1f,
    float* __restrict__ pre,
    const float* __restrict__ dec_w, ushort_t* __restrict__ bhi,
    ushort_t* __restrict__ blo, int do_split) {
  if (blockIdx.x >= 128) {
    if (!do_split) return;
    const int pid = blockIdx.x - 128;
    const int nt = pid >> 4, ks = pid & 15;
    const int tid = threadIdx.x;
#pragma unroll
    for (int h = 0; h < 2; ++h) {
      int us = h * 256 + tid;
      int r = us >> 2, kg = us & 3;
      const float* src = dec_w + (size_t)(nt * 128 + r) * HID + ks * 32 + kg * 8;
      float4 v0 = *(const float4*)src;
      float4 v1 = *(const float4*)(src + 4);
      float av[8] = {v0.x, v0.y, v0.z, v0.w, v1.x, v1.y, v1.z, v1.w};
      s8v hi, lo;
#pragma unroll
      for (int j = 0; j < 8; ++j) {
        unsigned short hh = f2bf_rne(av[j]);
        hi[j] = (short)hh;
        lo[j] = (short)f2bf_rne(av[j] - bf2f(hh));
      }
      size_t base = ((size_t)(nt * 16 + ks) * 512 + unit_swz(r, kg)) * 8;
      *(s8v*)(bhi + base) = hi;
      *(s8v*)(blo + base) = lo;
    }
    return;
  }
  __shared__ s8v Ah[512], Al[512], Bh[512], Bl[512];
  const int mt = blockIdx.x & 31, nt = blockIdx.x >> 5;
  const int tid = threadIdx.x;
  const int lane = tid & 63, wave = tid >> 6;
  const int wm = wave >> 1, wn = wave & 1;
  const int m0 = mt * 128, n0 = nt * 128;
  f4v acc[4][4] = {};

  for (int ks = 0; ks < 16; ++ks) {
    const int k0 = ks * 32;
#pragma unroll
    for (int c = 0; c < 2; ++c) {
      int idx = c * 256 + tid;
      int r = idx >> 2, kg = idx & 3;
      int kgp = kg ^ (r & 3);
      int t_ = tok[m0 + r];
      const float* as = emb + (size_t)t_ * HID + k0 + kg * 8;
      float4 a0 = *(const float4*)as;
      float4 a1 = *(const float4*)(as + 4);
      float av[8] = {a0.x, a0.y, a0.z, a0.w, a1.x, a1.y, a1.z, a1.w};
      s8v ah, al;
#pragma unroll
      for (int j = 0; j < 8; ++j) {
        unsigned short h = f2bf_rne(av[j]);
        ah[j] = (short)h;
        al[j] = (short)f2bf_rne(av[j] - bf2f(h));
      }
      Ah[r * 4 + kgp] = ah;  Al[r * 4 + kgp] = al;
      const float* bs = w1 + (size_t)(n0 + r) * 1024 + k0 + kg * 8;
      float4 b0 = *(const float4*)bs;
      float4 b1v = *(const float4*)(bs + 4);
      float bv[8] = {b0.x, b0.y, b0.z, b0.w, b1v.x, b1v.y, b1v.z, b1v.w};
      s8v bh, bl;
#pragma unroll
      for (int j = 0; j < 8; ++j) {
        unsigned short h = f2bf_rne(bv[j]);
        bh[j] = (short)h;
        bl[j] = (short)f2bf_rne(bv[j] - bf2f(h));
      }
      Bh[r * 4 + kgp] = bh;  Bl[r * 4 + kgp] = bl;
    }
    __syncthreads();
    s8v afh[4], afl[4], bfh[4], bfl[4];
#pragma unroll
    for (int f = 0; f < 4; ++f) {
      int rA = wm * 64 + f * 16 + (lane & 15);
      afh[f] = Ah[rA * 4 + ((lane >> 4) ^ (rA & 3))];
      afl[f] = Al[rA * 4 + ((lane >> 4) ^ (rA & 3))];
      int rB = wn * 64 + f * 16 + (lane & 15);
      bfh[f] = Bh[rB * 4 + ((lane >> 4) ^ (rB & 3))];
      bfl[f] = Bl[rB * 4 + ((lane >> 4) ^ (rB & 3))];
    }
#pragma unroll
    for (int i = 0; i < 4; ++i)
#pragma unroll
      for (int j = 0; j < 4; ++j)
        acc[i][j] = MFMA16(afh[i], bfh[j], acc[i][j]);
#pragma unroll
    for (int i = 0; i < 4; ++i)
#pragma unroll
      for (int j = 0; j < 4; ++j)
        acc[i][j] = MFMA16(afl[i], bfh[j], acc[i][j]);
#pragma unroll
    for (int i = 0; i < 4; ++i)
#pragma unroll
      for (int j = 0; j < 4; ++j)
        acc[i][j] = MFMA16(afh[i], bfl[j], acc[i][j]);
    __syncthreads();
  }
#pragma unroll
  for (int j = 0; j < 4; ++j) {
    int col = n0 + wn * 64 + j * 16 + (lane & 15);
    float bias = b1f[col];
#pragma unroll
    for (int i = 0; i < 4; ++i)
#pragma unroll
      for (int rg = 0; rg < 4; ++rg) {
        int row = m0 + wm * 64 + i * 16 + (lane >> 4) * 4 + rg;
        pre[(size_t)row * HID + col] = acc[i][j][rg] + bias;
      }
  }
}

// ---------------------------------------------------------------------------
// K2: barrier-free persistent scan (round-5 version, 459 us measured).
// ---------------------------------------------------------------------------
__global__ __launch_bounds__(512) void scan_kernel(
    const float* __restrict__ w1, const float* __restrict__ pre,
    unsigned long long* hbuf,
    ushort_t* __restrict__ o_hi, ushort_t* __restrict__ o_lo,
    float* __restrict__ h_last_out) {
  __shared__ float wLds[16384];
  __shared__ float hs[2][512];
  __shared__ float part[2][528];

  const int bp = blockIdx.x & 7;
  const int sg = blockIdx.x >> 3;
  const int b0 = bp * 2, b1 = b0 + 1;
  const int tid = threadIdx.x;

#pragma unroll
  for (int k = 0; k < 8; ++k) {
    int uid = k * 512 + tid;
    int r = uid >> 7, u = uid & 127;
    float4 v = *(const float4*)(w1 + (size_t)(sg * 32 + r) * 1024 + 512 + u * 4);
    int dst = r * 512 + (u >> 3) * 32 + (((u & 7) ^ (r & 7)) << 2);
    *(float4*)(&wLds[dst]) = v;
  }
  __syncthreads();

  const int i = tid & 31, s = tid >> 5;
  const int rowbase = i * 512 + s * 32;
  const int isw = i & 7;

  for (int t = 0; t < T_STEPS; ++t) {
    const int cur = t & 1, nxt = cur ^ 1;

    float pv = 0.f;
    if (tid < 64) {
      int bl = tid >> 5, ii = tid & 31;
      pv = pre[(size_t)(t * BATCH + b0 + bl) * HID + sg * 32 + ii];
    }

    unsigned long long* p0 = hbuf + ((size_t)cur * BATCH + b0) * HID + tid;
    unsigned long long* p1 = hbuf + ((size_t)cur * BATCH + b1) * HID + tid;
    unsigned long long e0 = __hip_atomic_load(p0, __ATOMIC_RELAXED, __HIP_MEMORY_SCOPE_AGENT);
    unsigned long long e1 = __hip_atomic_load(p1, __ATOMIC_RELAXED, __HIP_MEMORY_SCOPE_AGENT);
    int spins = 0;
    while ((unsigned)(e0 >> 32) != (unsigned)t || (unsigned)(e1 >> 32) != (unsigned)t) {
      __builtin_amdgcn_s_sleep(1);
      if ((unsigned)(e0 >> 32) != (unsigned)t)
        e0 = __hip_atomic_load(p0, __ATOMIC_RELAXED, __HIP_MEMORY_SCOPE_AGENT);
      if ((unsigned)(e1 >> 32) != (unsigned)t)
        e1 = __hip_atomic_load(p1, __ATOMIC_RELAXED, __HIP_MEMORY_SCOPE_AGENT);
      if (++spins > (1 << 20)) break;
    }
    hs[0][tid] = __uint_as_float((unsigned)e0);
    hs[1][tid] = __uint_as_float((unsigned)e1);
    __syncthreads();

    float a0 = 0.f, a1 = 0.f;
#pragma unroll
    for (int u = 0; u < 8; ++u) {
      float4 w = *(const float4*)(&wLds[rowbase + ((u ^ isw) << 2)]);
      float4 h0 = *(const float4*)(&hs[0][s * 32 + (u << 2)]);
      float4 h1 = *(const float4*)(&hs[1][s * 32 + (u << 2)]);
      a0 += w.x * h0.x + w.y * h0.y + w.z * h0.z + w.w * h0.w;
      a1 += w.x * h1.x + w.y * h1.y + w.z * h1.z + w.w * h1.w;
    }
    part[0][s * 33 + i] = a0;
    part[1][s * 33 + i] = a1;
    __syncthreads();

    if (tid < 64) {
      int bl = tid >> 5, ii = tid & 31;
      float ssum = 0.f;
#pragma unroll
      for (int ss = 0; ss < 16; ++ss) ssum += part[bl][ss * 33 + ii];
      ssum += pv;
      float hn = tanhf(ssum);
      int b = b0 + bl;
      unsigned long long ev = ((unsigned long long)(unsigned)(t + 1) << 32) |
                              (unsigned long long)__float_as_uint(hn);
      __hip_atomic_store(hbuf + ((size_t)nxt * BATCH + b) * HID + sg * 32 + ii, ev,
                         __ATOMIC_RELAXED, __HIP_MEMORY_SCOPE_AGENT);
      int m = t * BATCH + b;
      int mt = m >> 7, r = m & 127;
      int kg = ii >> 3, e = ii & 7;
      size_t ao = ((size_t)(mt * 16 + sg) * 512 + unit_swz(r, kg)) * 8 + e;
      unsigned short hi_ = f2bf_rne(hn);
      o_hi[ao] = hi_;
      o_lo[ao] = f2bf_rne(hn - bf2f(hi_));
      if (t == T_STEPS - 1) h_last_out[(size_t)b * HID + sg * 32 + ii] = hn;
    }
  }
}

// ---------------------------------------------------------------------------
// K3 v6: identical structure to round-8 v5 EXCEPT the epilogue stores are
// nontemporal (nt bit): the 524 MB fp32 logit stream bypasses L2/L3
// allocation, so the 82 MB A/B operand set stays L3-resident (FETCH_SIZE
// was 4x the minimum from write-stream thrash).
// ---------------------------------------------------------------------------
__global__ __launch_bounds__(512, 2) void dec_gemm_v3(
    const ushort_t* __restrict__ ahi, const ushort_t* __restrict__ alo,
    const ushort_t* __restrict__ bhi, const ushort_t* __restrict__ blo,
    const float* __restrict__ dec_b, float* __restrict__ out) {
  extern __shared__ s8v SB[];   // 2 x 4096 units of 16B
  const int bid = blockIdx.x;
  const int wg  = (bid & 7) * 250 + (bid >> 3);   // XCD-bijective (2000 = 8*250)
  const int mt2 = wg & 15, nt2 = wg >> 4;         // mt fastest: B-panel L2 reuse
  const int tid = threadIdx.x, lane = tid & 63, wv = tid >> 6;
  const int wm = wv >> 2, wn = wv & 3;            // 2 x 4 wave grid
  const int lane32 = lane & 31, kh = lane >> 5;
  const int tB = wn >> 1;

  const ushort_t* gsrc;
  int gtile;
  if (wv < 4) { gsrc = (wv < 2) ? ahi : alo; gtile = mt2 * 2 + (wv & 1); }
  else        { gsrc = (wv < 6) ? bhi : blo; gtile = nt2 * 2 + (wv & 1); }

  // precomputed LDS unit indices (constant across kt; lo image = +1024)
  int uB_[2][2], uA_[4][2];
#pragma unroll
  for (int tn = 0; tn < 2; ++tn)
#pragma unroll
    for (int s = 0; s < 2; ++s)
      uB_[tn][s] = (4 + tB) * 512 +
                   unit_swz((wn & 1) * 64 + tn * 32 + lane32, s * 2 + kh);
#pragma unroll
  for (int tm = 0; tm < 4; ++tm)
#pragma unroll
    for (int s = 0; s < 2; ++s)
      uA_[tm][s] = wm * 512 + unit_swz(tm * 32 + lane32, s * 2 + kh);

  f16v acc[4][2] = {};   // [tm][tn] 32x32 tiles; 128 VGPRs

  // ---- prologue: stage kt=0 -> buf0, kt=1 -> buf1 ----
  {
    const char* g0 = (const char*)(gsrc + (size_t)(gtile * 16 + 0) * 4096);
    const char* g1 = (const char*)(gsrc + (size_t)(gtile * 16 + 1) * 4096);
    char* l0 = (char*)SB + wv * 8192;
    char* l1 = (char*)SB + 65536 + wv * 8192;
#pragma unroll
    for (int p = 0; p < 8; ++p) gload16(g0 + p * 1024 + (size_t)lane * 16, l0 + p * 1024);
#pragma unroll
    for (int p = 0; p < 8; ++p) gload16(g1 + p * 1024 + (size_t)lane * 16, l1 + p * 1024);
    asm volatile("s_waitcnt vmcnt(8)" ::: "memory");   // kt0 landed
    __builtin_amdgcn_sched_barrier(0);
    __builtin_amdgcn_s_barrier();
    __builtin_amdgcn_sched_barrier(0);
  }

  for (int kt = 0; kt < KT_DEC; ++kt) {
    const int c = kt & 1;
    const s8v* B0 = SB + c * 4096;

    s8v bh[2][2], bl[2][2], ah[4][2], al[4][2];
    // group 1: B (8) + A tm0/1 (8)
#pragma unroll
    for (int tn = 0; tn < 2; ++tn)
#pragma unroll
      for (int s = 0; s < 2; ++s) {
        bh[tn][s] = B0[uB_[tn][s]];
        bl[tn][s] = B0[1024 + uB_[tn][s]];
      }
#pragma unroll
    for (int tm = 0; tm < 2; ++tm)
#pragma unroll
      for (int s = 0; s < 2; ++s) {
        ah[tm][s] = B0[uA_[tm][s]];
        al[tm][s] = B0[1024 + uA_[tm][s]];
      }
    __builtin_amdgcn_sched_barrier(0);   // group1 emitted before group2
    // group 2: A tm2/3 (8) — completes under cluster0
#pragma unroll
    for (int tm = 2; tm < 4; ++tm)
#pragma unroll
      for (int s = 0; s < 2; ++s) {
        ah[tm][s] = B0[uA_[tm][s]];
        al[tm][s] = B0[1024 + uA_[tm][s]];
      }
    asm volatile("s_waitcnt lgkmcnt(8)" ::: "memory");  // group1 ready
    __builtin_amdgcn_sched_barrier(0);

    __builtin_amdgcn_s_setprio(1);
    // cluster 0: tm0/1 — per-acc order: s0 hh, s1 hh, s0 lh, s1 lh, s0 hl, s1 hl
#pragma unroll
    for (int s = 0; s < 2; ++s)
#pragma unroll
      for (int tn = 0; tn < 2; ++tn) {
        acc[0][tn] = MFMA32(ah[0][s], bh[tn][s], acc[0][tn]);
        acc[1][tn] = MFMA32(ah[1][s], bh[tn][s], acc[1][tn]);
      }
#pragma unroll
    for (int s = 0; s < 2; ++s)
#pragma unroll
      for (int tn = 0; tn < 2; ++tn) {
        acc[0][tn] = MFMA32(al[0][s], bh[tn][s], acc[0][tn]);
        acc[1][tn] = MFMA32(al[1][s], bh[tn][s], acc[1][tn]);
      }
#pragma unroll
    for (int s = 0; s < 2; ++s)
#pragma unroll
      for (int tn = 0; tn < 2; ++tn) {
        acc[0][tn] = MFMA32(ah[0][s], bl[tn][s], acc[0][tn]);
        acc[1][tn] = MFMA32(ah[1][s], bl[tn][s], acc[1][tn]);
      }
    __builtin_amdgcn_s_setprio(0);

    asm volatile("s_waitcnt lgkmcnt(0)" ::: "memory");  // all buf-c reads done
    __builtin_amdgcn_sched_barrier(0);
    __builtin_amdgcn_s_barrier();          // buf c free for overwrite
    __builtin_amdgcn_sched_barrier(0);
    if (kt + 2 < KT_DEC) {                 // stage kt+2 -> buf c (hides under cluster1)
      const char* g = (const char*)(gsrc + (size_t)(gtile * 16 + kt + 2) * 4096);
      char* l = (char*)SB + c * 65536 + wv * 8192;
#pragma unroll
      for (int p = 0; p < 8; ++p) gload16(g + p * 1024 + (size_t)lane * 16, l + p * 1024);
    }
    __builtin_amdgcn_sched_barrier(0);     // stage issued before cluster1

    __builtin_amdgcn_s_setprio(1);
    // cluster 1: tm2/3
#pragma unroll
    for (int s = 0; s < 2; ++s)
#pragma unroll
      for (int tn = 0; tn < 2; ++tn) {
        acc[2][tn] = MFMA32(ah[2][s], bh[tn][s], acc[2][tn]);
        acc[3][tn] = MFMA32(ah[3][s], bh[tn][s], acc[3][tn]);
      }
#pragma unroll
    for (int s = 0; s < 2; ++s)
#pragma unroll
      for (int tn = 0; tn < 2; ++tn) {
        acc[2][tn] = MFMA32(al[2][s], bh[tn][s], acc[2][tn]);
        acc[3][tn] = MFMA32(al[3][s], bh[tn][s], acc[3][tn]);
      }
#pragma unroll
    for (int s = 0; s < 2; ++s)
#pragma unroll
      for (int tn = 0; tn < 2; ++tn) {
        acc[2][tn] = MFMA32(ah[2][s], bl[tn][s], acc[2][tn]);
        acc[3][tn] = MFMA32(ah[3][s], bl[tn][s], acc[3][tn]);
      }
    __builtin_amdgcn_s_setprio(0);

    if (kt + 2 < KT_DEC) {
      asm volatile("s_waitcnt vmcnt(8)" ::: "memory");  // kt+1 landed
    } else {
      asm volatile("s_waitcnt vmcnt(0)" ::: "memory");  // tail drain
    }
    __builtin_amdgcn_sched_barrier(0);
    __builtin_amdgcn_s_barrier();          // kt+1 visible to all waves
    __builtin_amdgcn_sched_barrier(0);
  }

  const int m0 = mt2 * 256, n0 = nt2 * 256;
#pragma unroll
  for (int tn = 0; tn < 2; ++tn) {
    int col = n0 + wn * 64 + tn * 32 + lane32;
    float bias = dec_b[col];
#pragma unroll
    for (int tm = 0; tm < 4; ++tm) {
      int rowb = m0 + wm * 128 + tm * 32 + 4 * kh;
#pragma unroll
      for (int reg = 0; reg < 16; ++reg) {
        int row = rowb + (reg & 3) + 8 * (reg >> 2);
        __builtin_nontemporal_store(acc[tm][tn][reg] + bias,
                                    &out[(size_t)row * VOCAB + col]);
      }
    }
  }
}

// ---------------------------------------------------------------------------
// K3 fallback (ws too small for presplit): unchanged math, nt stores.
// ---------------------------------------------------------------------------
__global__ __launch_bounds__(256, 2) void dec_gemm_fb(
    const ushort_t* __restrict__ o_hi, const ushort_t* __restrict__ o_lo,
    const float* __restrict__ dec_w, const float* __restrict__ dec_b,
    float* __restrict__ out) {
  __shared__ s8v Ah[512], Al[512], Bh[512], Bl[512];
  const int mt = blockIdx.x, nt = blockIdx.y;
  const int tid = threadIdx.x;
  const int lane = tid & 63, wave = tid >> 6;
  const int wm = wave >> 1, wn = wave & 1;
  const int kgl = lane >> 4, lr = lane & 15;
  const int m0 = mt * 128, n0 = nt * 128;
  f4v acc[4][4] = {};

  for (int ks = 0; ks < KT_DEC; ++ks) {
    const int k0 = ks * 32;
#pragma unroll
    for (int c = 0; c < 2; ++c) {
      int idx = c * 256 + tid;
      size_t abase = (size_t)(mt * 16 + ks) * 4096 + (size_t)idx * 8;
      Ah[idx] = *(const s8v*)(o_hi + abase);
      Al[idx] = *(const s8v*)(o_lo + abase);
      int r = idx >> 2, kg = idx & 3;
      const float* bs = dec_w + (size_t)(n0 + r) * HID + k0 + kg * 8;
      float4 b0 = *(const float4*)bs;
      float4 b1v = *(const float4*)(bs + 4);
      float bv[8] = {b0.x, b0.y, b0.z, b0.w, b1v.x, b1v.y, b1v.z, b1v.w};
      s8v bh, bl;
#pragma unroll
      for (int j = 0; j < 8; ++j) {
        unsigned short h = f2bf_rne(bv[j]);
        bh[j] = (short)h;
        bl[j] = (short)f2bf_rne(bv[j] - bf2f(h));
      }
      int ub = unit_swz(r, kg);
      Bh[ub] = bh;  Bl[ub] = bl;
    }
    __syncthreads();
    s8v afh[4], afl[4], bfh[4], bfl[4];
#pragma unroll
    for (int f = 0; f < 4; ++f) {
      int rA = wm * 64 + f * 16 + lr;
      int uA = unit_swz(rA, kgl);
      afh[f] = Ah[uA];  afl[f] = Al[uA];
      int rB = wn * 64 + f * 16 + lr;
      int uB = unit_swz(rB, kgl);
      bfh[f] = Bh[uB];  bfl[f] = Bl[uB];
    }
#pragma unroll
    for (int i = 0; i < 4; ++i)
#pragma unroll
      for (int j = 0; j < 4; ++j)
        acc[i][j] = MFMA16(afh[i], bfh[j], acc[i][j]);
#pragma unroll
    for (int i = 0; i < 4; ++i)
#pragma unroll
      for (int j = 0; j < 4; ++j)
        acc[i][j] = MFMA16(afl[i], bfh[j], acc[i][j]);
#pragma unroll
    for (int i = 0; i < 4; ++i)
#pragma unroll
      for (int j = 0; j < 4; ++j)
        acc[i][j] = MFMA16(afh[i], bfl[j], acc[i][j]);
    __syncthreads();
  }
#pragma unroll
  for (int j = 0; j < 4; ++j) {
    int col = n0 + wn * 64 + j * 16 + lr;
    float bias = dec_b[col];
#pragma unroll
    for (int i = 0; i < 4; ++i)
#pragma unroll
      for (int rg = 0; rg < 4; ++rg) {
        int row = m0 + wm * 64 + i * 16 + (lane >> 4) * 4 + rg;
        __builtin_nontemporal_store(acc[i][j][rg] + bias,
                                    &out[(size_t)row * VOCAB + col]);
      }
  }
}

// ---------------------------------------------------------------------------
// Workspace layout (bytes):
//   [0,       128 KiB)   hbuf: u64[2][16][512] (tag|f32)  (zeroed each call)
//   [1 MiB,    9 MiB)    pre : 4096 x 512 f32
//   [16 MiB,  20 MiB)    o_hi: tile-ready A hi (32x16 tiles x 8 KiB)
//   [20 MiB,  24 MiB)    o_lo: tile-ready A lo
//   [24 MiB,  ~55 MiB)   bhi : tile-ready dec_w hi (250x16 tiles x 8 KiB)
//   [56 MiB,  ~87 MiB)   blo : tile-ready dec_w lo
// ---------------------------------------------------------------------------
extern "C" void kernel_launch(void* const* d_in, const int* in_sizes, int n_in,
                              void* d_out, int out_size, void* d_ws, size_t ws_size,
                              hipStream_t stream) {
  (void)in_sizes; (void)n_in; (void)out_size;
  const int*   tok   = (const int*)d_in[0];
  const float* emb   = (const float*)d_in[2];
  const float* w1    = (const float*)d_in[3];
  const float* b1    = (const float*)d_in[4];
  const float* dec_w = (const float*)d_in[5];
  const float* dec_b = (const float*)d_in[6];
  char* ws = (char*)d_ws;
  unsigned long long* hbuf = (unsigned long long*)(ws);
  float* pre  = (float*)(ws + (1u << 20));
  ushort_t* o_hi = (ushort_t*)(ws + 16u * (1u << 20));
  ushort_t* o_lo = (ushort_t*)(ws + 20u * (1u << 20));
  ushort_t* bhi  = (ushort_t*)(ws + 24u * (1u << 20));
  ushort_t* blo  = (ushort_t*)(ws + 56u * (1u << 20));
  float* out = (float*)d_out;

  const int big = (ws_size >= (size_t)92 * 1024 * 1024) ? 1 : 0;

  hipMemsetAsync(ws, 0, 131072, stream);   // tag=0, h0=0
  head_kernel<<<dim3(4128), dim3(256), 0, stream>>>(
      tok, emb, w1, b1, pre, dec_w, bhi, blo, big);
  scan_kernel<<<dim3(128), dim3(512), 0, stream>>>(
      w1, pre, hbuf, o_hi, o_lo, out + (size_t)M_TOT * VOCAB);
  if (big) {
    hipFuncSetAttribute((const void*)dec_gemm_v3,
                        hipFuncAttributeMaxDynamicSharedMemorySize, 131072);
    dec_gemm_v3<<<dim3(2000), dim3(512), 131072, stream>>>(
        o_hi, o_lo, bhi, blo, dec_b, out);
  } else {
    dec_gemm_fb<<<dim3(32, 250), dim3(256), 0, stream>>>(o_hi, o_lo, dec_w, dec_b, out);
  }
}